// Round 1
// baseline (567.581 us; speedup 1.0000x reference)
//
#include <hip/hip_runtime.h>
#include <math.h>

#define N_NODES   50000
#define N_EDGES   800000
#define N_FEAT    128
#define HIDDEN    64
#define EMBED     300
#define N_CLASSES 10
#define N_GRAPHS  500
#define LEAKY     0.01f

// ---------------- degree / norm ----------------
__global__ void k_init_deg(float* deg) {
    int i = blockIdx.x * 256 + threadIdx.x;
    if (i < N_NODES) deg[i] = 1.0f;  // self-loop
}

__global__ void k_deg(const int* __restrict__ dst, float* deg) {
    int e = blockIdx.x * 256 + threadIdx.x;
    if (e < N_EDGES) atomicAdd(&deg[dst[e]], 1.0f);
}

__global__ void k_rsqrt(float* deg) {
    int i = blockIdx.x * 256 + threadIdx.x;
    if (i < N_NODES) deg[i] = rsqrtf(deg[i]);  // deg >= 1, finite
}

// ---------------- GEMM1: h = x @ W1  (50000x128 @ 128x64) ----------------
__global__ __launch_bounds__(256) void k_gemm1(const float* __restrict__ x,
                                               const float* __restrict__ W,
                                               float* __restrict__ h) {
    __shared__ float sW[N_FEAT * HIDDEN];  // 32 KB
    __shared__ float sx[4 * N_FEAT];       // 2 KB
    for (int i = threadIdx.x; i < N_FEAT * HIDDEN; i += 256) sW[i] = W[i];

    int base = blockIdx.x * 4;
    for (int i = threadIdx.x; i < 4 * N_FEAT; i += 256) {
        int n = base + (i >> 7);
        sx[i] = (n < N_NODES) ? x[n * N_FEAT + (i & 127)] : 0.0f;
    }
    __syncthreads();

    int f  = threadIdx.x & 63;
    int ln = threadIdx.x >> 6;
    int n  = base + ln;
    if (n < N_NODES) {
        float acc = 0.0f;
        #pragma unroll 8
        for (int k = 0; k < N_FEAT; ++k)
            acc = fmaf(sx[ln * N_FEAT + k], sW[k * HIDDEN + f], acc);
        h[n * HIDDEN + f] = acc;
    }
}

// ---------------- agg init: agg = h * dis^2 + b ----------------
__global__ void k_agg_init(const float* __restrict__ h, const float* __restrict__ dis,
                           const float* __restrict__ b, float* __restrict__ agg) {
    int i = blockIdx.x * 256 + threadIdx.x;
    if (i < N_NODES * HIDDEN) {
        int n = i >> 6, f = i & 63;
        float d = dis[n];
        agg[i] = fmaf(h[i], d * d, b[f]);
    }
}

// ---------------- edge scatter: agg[dst] += h[src] * dis[src]*dis[dst] ----------------
__global__ void k_scatter(const int* __restrict__ src, const int* __restrict__ dst,
                          const float* __restrict__ dis, const float* __restrict__ h,
                          float* agg) {
    long long tid = (long long)blockIdx.x * 256 + threadIdx.x;
    int e = (int)(tid >> 6);
    int f = (int)(tid & 63);
    if (e < N_EDGES) {
        int s = src[e], d = dst[e];
        float nrm = dis[s] * dis[d];
        atomicAdd(&agg[d * HIDDEN + f], h[s * HIDDEN + f] * nrm);
    }
}

// ---------------- GEMM2: h2 = relu(agg1) @ W2  (50000x64 @ 64x64) ----------------
__global__ __launch_bounds__(256) void k_gemm2(const float* __restrict__ a,
                                               const float* __restrict__ W,
                                               float* __restrict__ h) {
    __shared__ float sW[HIDDEN * HIDDEN];  // 16 KB
    __shared__ float sa[4 * HIDDEN];
    for (int i = threadIdx.x; i < HIDDEN * HIDDEN; i += 256) sW[i] = W[i];

    int base = blockIdx.x * 4;
    if (threadIdx.x < 4 * HIDDEN) {
        int n = base + (threadIdx.x >> 6);
        sa[threadIdx.x] = (n < N_NODES) ? fmaxf(a[n * HIDDEN + (threadIdx.x & 63)], 0.0f) : 0.0f;
    }
    __syncthreads();

    int f  = threadIdx.x & 63;
    int ln = threadIdx.x >> 6;
    int n  = base + ln;
    if (n < N_NODES) {
        float acc = 0.0f;
        #pragma unroll 8
        for (int k = 0; k < HIDDEN; ++k)
            acc = fmaf(sa[ln * HIDDEN + k], sW[k * HIDDEN + f], acc);
        h[n * HIDDEN + f] = acc;
    }
}

// ---------------- attention score: att_s[n] = leaky_relu(relu(agg2[n]) . att_w + att_b) ----------------
__global__ void k_att(const float* __restrict__ agg2, const float* __restrict__ att_w,
                      const float* __restrict__ att_b, float* __restrict__ att_s) {
    int n = blockIdx.x * 4 + (threadIdx.x >> 6);
    int f = threadIdx.x & 63;
    float v = 0.0f;
    if (n < N_NODES) v = fmaxf(agg2[n * HIDDEN + f], 0.0f) * att_w[f];
    #pragma unroll
    for (int o = 32; o > 0; o >>= 1) v += __shfl_down(v, o, 64);
    if (f == 0 && n < N_NODES) {
        float s = v + att_b[0];
        att_s[n] = (s > 0.0f) ? s : LEAKY * s;
    }
}

// ---------------- graph boundaries (batch is sorted) ----------------
__global__ void k_gbounds_init(int* gs, int* ge) {
    int i = blockIdx.x * 256 + threadIdx.x;
    if (i < N_GRAPHS) { gs[i] = 0; ge[i] = 0; }
}

__global__ void k_gbounds(const int* __restrict__ batch, int* gs, int* ge) {
    int n = blockIdx.x * 256 + threadIdx.x;
    if (n < N_NODES) {
        int b = batch[n];
        if (n == 0 || batch[n - 1] != b) gs[b] = n;
        if (n == N_NODES - 1 || batch[n + 1] != b) ge[b] = n + 1;
    }
}

// ---------------- pooled readout: g[gid] = sum softmax(att_s) * relu(agg2) ----------------
__global__ __launch_bounds__(64) void k_pool(const float* __restrict__ agg2,
                                             const float* __restrict__ att_s,
                                             const int* __restrict__ gs,
                                             const int* __restrict__ ge,
                                             float* __restrict__ g) {
    int gid = blockIdx.x;
    int f = threadIdx.x;
    int s = gs[gid], e = ge[gid];

    float m = -INFINITY;
    for (int n = s + f; n < e; n += 64) m = fmaxf(m, att_s[n]);
    #pragma unroll
    for (int o = 32; o > 0; o >>= 1) m = fmaxf(m, __shfl_xor(m, o, 64));

    float z = 0.0f;
    for (int n = s + f; n < e; n += 64) z += expf(att_s[n] - m);
    #pragma unroll
    for (int o = 32; o > 0; o >>= 1) z += __shfl_xor(z, o, 64);

    float acc = 0.0f;
    if (e > s) {
        float inv = 1.0f / z;
        for (int n = s; n < e; ++n) {
            float w = expf(att_s[n] - m) * inv;
            acc = fmaf(w, fmaxf(agg2[n * HIDDEN + f], 0.0f), acc);
        }
    }
    g[gid * HIDDEN + f] = acc;
}

// ---------------- head MLPs ----------------
__global__ void k_mlp1(const float* __restrict__ g, const float* __restrict__ W,
                       const float* __restrict__ b, float* __restrict__ t1) {
    int idx = blockIdx.x * 256 + threadIdx.x;
    if (idx < N_GRAPHS * EMBED) {
        int r = idx / EMBED, c = idx - r * EMBED;
        float acc = b[c];
        #pragma unroll 8
        for (int k = 0; k < HIDDEN; ++k) acc = fmaf(g[r * HIDDEN + k], W[k * EMBED + c], acc);
        t1[idx] = acc;
    }
}

__global__ void k_mlp2(const float* __restrict__ t1, const float* __restrict__ W,
                       const float* __restrict__ b, float* __restrict__ t2) {
    int idx = blockIdx.x * 256 + threadIdx.x;
    if (idx < N_GRAPHS * 128) {
        int r = idx >> 7, c = idx & 127;
        float acc = b[c];
        for (int k = 0; k < EMBED; ++k) acc = fmaf(t1[r * EMBED + k], W[k * 128 + c], acc);
        t2[idx] = fmaxf(acc, 0.0f);
    }
}

__global__ void k_mlp3(const float* __restrict__ t2, const float* __restrict__ W,
                       const float* __restrict__ b, float* __restrict__ out) {
    int idx = blockIdx.x * 256 + threadIdx.x;
    if (idx < N_GRAPHS * N_CLASSES) {
        int r = idx / N_CLASSES, c = idx - r * N_CLASSES;
        float acc = b[c];
        #pragma unroll 8
        for (int k = 0; k < 128; ++k) acc = fmaf(t2[r * 128 + k], W[k * N_CLASSES + c], acc);
        out[idx] = acc;
    }
}

extern "C" void kernel_launch(void* const* d_in, const int* in_sizes, int n_in,
                              void* d_out, int out_size, void* d_ws, size_t ws_size,
                              hipStream_t stream) {
    const float* x      = (const float*)d_in[0];
    const int*   ei     = (const int*)d_in[1];      // [2][N_EDGES], int32
    const int*   batch  = (const int*)d_in[2];
    const float* W1     = (const float*)d_in[3];
    const float* b1     = (const float*)d_in[4];
    const float* W2     = (const float*)d_in[5];
    const float* b2     = (const float*)d_in[6];
    const float* att_w  = (const float*)d_in[7];
    const float* att_b  = (const float*)d_in[8];
    const float* proj_w = (const float*)d_in[9];
    const float* proj_b = (const float*)d_in[10];
    const float* cls_w1 = (const float*)d_in[11];
    const float* cls_b1 = (const float*)d_in[12];
    const float* cls_w2 = (const float*)d_in[13];
    const float* cls_b2 = (const float*)d_in[14];
    float* out = (float*)d_out;

    const int* e_src = ei;
    const int* e_dst = ei + N_EDGES;

    // workspace layout (floats)
    float* ws    = (float*)d_ws;
    float* dis   = ws;                       // 50000
    float* bufA  = dis + 50048;              // h1 / h2:   N*64
    float* bufB  = bufA + N_NODES * HIDDEN;  // agg1/agg2: N*64
    float* att_s = bufB + N_NODES * HIDDEN;  // 50000
    float* gbuf  = att_s + 50048;            // 500*64
    float* t1    = gbuf + N_GRAPHS * HIDDEN; // 500*300
    float* t2    = t1 + N_GRAPHS * EMBED;    // 500*128
    int*   gs    = (int*)(t2 + N_GRAPHS * 128);
    int*   ge    = gs + N_GRAPHS;

    const int NB_N    = (N_NODES + 255) / 256;
    const int NB_E    = (N_EDGES + 255) / 256;
    const int NB_NF   = (N_NODES * HIDDEN + 255) / 256;
    const int NB_EF   = (int)(((long long)N_EDGES * HIDDEN + 255) / 256);
    const int NB_ROW4 = (N_NODES + 3) / 4;

    // degrees -> dis
    k_init_deg<<<NB_N, 256, 0, stream>>>(dis);
    k_deg<<<NB_E, 256, 0, stream>>>(e_dst, dis);
    k_rsqrt<<<NB_N, 256, 0, stream>>>(dis);

    // conv1
    k_gemm1<<<NB_ROW4, 256, 0, stream>>>(x, W1, bufA);
    k_agg_init<<<NB_NF, 256, 0, stream>>>(bufA, dis, b1, bufB);
    k_scatter<<<NB_EF, 256, 0, stream>>>(e_src, e_dst, dis, bufA, bufB);

    // conv2 (relu fused into gemm2 load)
    k_gemm2<<<NB_ROW4, 256, 0, stream>>>(bufB, W2, bufA);
    k_agg_init<<<NB_NF, 256, 0, stream>>>(bufA, dis, b2, bufB);
    k_scatter<<<NB_EF, 256, 0, stream>>>(e_src, e_dst, dis, bufA, bufB);

    // attention + segment softmax + pooling (relu(bufB) applied in-kernel)
    k_att<<<NB_ROW4, 256, 0, stream>>>(bufB, att_w, att_b, att_s);
    k_gbounds_init<<<(N_GRAPHS + 255) / 256, 256, 0, stream>>>(gs, ge);
    k_gbounds<<<NB_N, 256, 0, stream>>>(batch, gs, ge);
    k_pool<<<N_GRAPHS, 64, 0, stream>>>(bufB, att_s, gs, ge, gbuf);

    // head
    k_mlp1<<<(N_GRAPHS * EMBED + 255) / 256, 256, 0, stream>>>(gbuf, proj_w, proj_b, t1);
    k_mlp2<<<(N_GRAPHS * 128 + 255) / 256, 256, 0, stream>>>(t1, cls_w1, cls_b1, t2);
    k_mlp3<<<(N_GRAPHS * N_CLASSES + 255) / 256, 256, 0, stream>>>(t2, cls_w2, cls_b2, out);
}

// Round 2
// 348.560 us; speedup vs baseline: 1.6284x; 1.6284x over previous
//
#include <hip/hip_runtime.h>
#include <math.h>

#define N_NODES   50000
#define N_EDGES   800000
#define N_FEAT    128
#define HIDDEN    64
#define EMBED     300
#define N_CLASSES 10
#define N_GRAPHS  500
#define LEAKY     0.01f
#define SCAN_BLOCKS ((N_NODES + 255) / 256)  // 196
#define G1_ROWS   32

// ---------------- CSR build ----------------
__global__ void k_zero(int* deg, int* cursor) {
    int i = blockIdx.x * 256 + threadIdx.x;
    if (i < N_NODES) { deg[i] = 0; cursor[i] = 0; }
}

__global__ void k_deg(const int* __restrict__ dst, int* deg) {
    int e = blockIdx.x * 256 + threadIdx.x;
    if (e < N_EDGES) atomicAdd(&deg[dst[e]], 1);
}

// block-local exclusive scan of deg -> row_start; block totals -> partials; dis = rsqrt(deg+1)
__global__ __launch_bounds__(256) void k_scan1(const int* __restrict__ deg, int* row_start,
                                               int* partials, float* dis) {
    __shared__ int wsum[4];
    int i = blockIdx.x * 256 + threadIdx.x;
    int v = (i < N_NODES) ? deg[i] : 0;
    int lane = threadIdx.x & 63, wid = threadIdx.x >> 6;
    int s = v;
    #pragma unroll
    for (int off = 1; off < 64; off <<= 1) {
        int t = __shfl_up(s, off, 64);
        if (lane >= off) s += t;
    }
    if (lane == 63) wsum[wid] = s;
    __syncthreads();
    int woff = 0;
    for (int w = 0; w < wid; ++w) woff += wsum[w];
    if (i < N_NODES) {
        row_start[i] = woff + s - v;             // block-local exclusive
        dis[i] = rsqrtf((float)(deg[i] + 1));    // +1 self-loop
    }
    if (threadIdx.x == 255) partials[blockIdx.x] = woff + s;
}

// exclusive scan of the 196 block totals (single block)
__global__ __launch_bounds__(256) void k_scan2(int* partials) {
    __shared__ int wsum[4];
    int v = (threadIdx.x < SCAN_BLOCKS) ? partials[threadIdx.x] : 0;
    int lane = threadIdx.x & 63, wid = threadIdx.x >> 6;
    int s = v;
    #pragma unroll
    for (int off = 1; off < 64; off <<= 1) {
        int t = __shfl_up(s, off, 64);
        if (lane >= off) s += t;
    }
    if (lane == 63) wsum[wid] = s;
    __syncthreads();
    int woff = 0;
    for (int w = 0; w < wid; ++w) woff += wsum[w];
    if (threadIdx.x < SCAN_BLOCKS) partials[threadIdx.x] = woff + s - v;
}

__global__ void k_scan3(int* row_start, const int* __restrict__ partials) {
    int i = blockIdx.x * 256 + threadIdx.x;
    if (i < N_NODES) row_start[i] += partials[blockIdx.x];
    if (i == 0) row_start[N_NODES] = N_EDGES;
}

__global__ void k_fill(const int* __restrict__ src, const int* __restrict__ dst,
                       const float* __restrict__ dis, const int* __restrict__ row_start,
                       int* cursor, int* col, float* nrm) {
    int e = blockIdx.x * 256 + threadIdx.x;
    if (e < N_EDGES) {
        int s = src[e], d = dst[e];
        int pos = row_start[d] + atomicAdd(&cursor[d], 1);
        col[pos] = s;
        nrm[pos] = dis[s] * dis[d];
    }
}

// ---------------- GEMM1: h = x @ W1  (50000x128 @ 128x64), 32 rows/block ----------------
__global__ __launch_bounds__(256) void k_gemm1(const float* __restrict__ x,
                                               const float* __restrict__ W,
                                               float* __restrict__ h) {
    __shared__ float sW[N_FEAT * HIDDEN];   // 32 KB, [k][f]
    __shared__ float sx[G1_ROWS * N_FEAT];  // 16 KB, [r][k]
    const float4* W4 = (const float4*)W;
    float4* sW4 = (float4*)sW;
    for (int i = threadIdx.x; i < N_FEAT * HIDDEN / 4; i += 256) sW4[i] = W4[i];

    int base = blockIdx.x * G1_ROWS;
    const float4* x4 = (const float4*)(x + (long long)base * N_FEAT);
    float4* sx4 = (float4*)sx;
    int lim = (N_NODES - base) * N_FEAT / 4;
    for (int i = threadIdx.x; i < G1_ROWS * N_FEAT / 4; i += 256)
        sx4[i] = (i < lim) ? x4[i] : make_float4(0.f, 0.f, 0.f, 0.f);
    __syncthreads();

    int f = threadIdx.x & 63, wid = threadIdx.x >> 6;
    float acc[8];
    #pragma unroll
    for (int u = 0; u < 8; ++u) acc[u] = 0.0f;

    for (int k4 = 0; k4 < N_FEAT / 4; ++k4) {
        float4 xr[8];
        #pragma unroll
        for (int u = 0; u < 8; ++u)
            xr[u] = *(const float4*)&sx[(wid * 8 + u) * N_FEAT + k4 * 4];
        #pragma unroll
        for (int kk = 0; kk < 4; ++kk) {
            float wv = sW[(k4 * 4 + kk) * HIDDEN + f];
            #pragma unroll
            for (int u = 0; u < 8; ++u) {
                const float* xp = (const float*)&xr[u];
                acc[u] = fmaf(xp[kk], wv, acc[u]);
            }
        }
    }
    #pragma unroll
    for (int u = 0; u < 8; ++u) {
        int n = base + wid * 8 + u;
        if (n < N_NODES) h[n * HIDDEN + f] = acc[u];
    }
}

// ---------------- fused gather: agg = sum_j nrm*h[col] + h*dis^2 + b ----------------
__global__ __launch_bounds__(256) void k_gather(const float* __restrict__ h,
                                                const int* __restrict__ col,
                                                const float* __restrict__ nrm,
                                                const int* __restrict__ row_start,
                                                const float* __restrict__ dis,
                                                const float* __restrict__ b,
                                                float* __restrict__ agg) {
    int node = blockIdx.x * 4 + (threadIdx.x >> 6);
    if (node >= N_NODES) return;
    int f = threadIdx.x & 63;
    int s = row_start[node], e = row_start[node + 1];
    float dv = dis[node];
    float acc0 = fmaf(h[node * HIDDEN + f], dv * dv, b[f]);
    float acc1 = 0.0f;
    int j = s;
    for (; j + 1 < e; j += 2) {
        int c0 = col[j], c1 = col[j + 1];
        float w0 = nrm[j], w1 = nrm[j + 1];
        acc0 = fmaf(w0, h[c0 * HIDDEN + f], acc0);
        acc1 = fmaf(w1, h[c1 * HIDDEN + f], acc1);
    }
    if (j < e) acc0 = fmaf(nrm[j], h[col[j] * HIDDEN + f], acc0);
    agg[node * HIDDEN + f] = acc0 + acc1;
}

// ---------------- GEMM2: h2 = relu(agg1) @ W2  (50000x64 @ 64x64), 32 rows/block ----------------
__global__ __launch_bounds__(256) void k_gemm2(const float* __restrict__ a,
                                               const float* __restrict__ W,
                                               float* __restrict__ h) {
    __shared__ float sW[HIDDEN * HIDDEN];   // 16 KB, [k][f]
    __shared__ float sa[G1_ROWS * HIDDEN];  // 8 KB
    const float4* W4 = (const float4*)W;
    float4* sW4 = (float4*)sW;
    for (int i = threadIdx.x; i < HIDDEN * HIDDEN / 4; i += 256) sW4[i] = W4[i];

    int base = blockIdx.x * G1_ROWS;
    const float4* a4 = (const float4*)(a + (long long)base * HIDDEN);
    float4* sa4 = (float4*)sa;
    int lim = (N_NODES - base) * HIDDEN / 4;
    for (int i = threadIdx.x; i < G1_ROWS * HIDDEN / 4; i += 256) {
        float4 v = (i < lim) ? a4[i] : make_float4(0.f, 0.f, 0.f, 0.f);
        v.x = fmaxf(v.x, 0.f); v.y = fmaxf(v.y, 0.f);
        v.z = fmaxf(v.z, 0.f); v.w = fmaxf(v.w, 0.f);
        sa4[i] = v;
    }
    __syncthreads();

    int f = threadIdx.x & 63, wid = threadIdx.x >> 6;
    float acc[8];
    #pragma unroll
    for (int u = 0; u < 8; ++u) acc[u] = 0.0f;

    for (int k4 = 0; k4 < HIDDEN / 4; ++k4) {
        float4 xr[8];
        #pragma unroll
        for (int u = 0; u < 8; ++u)
            xr[u] = *(const float4*)&sa[(wid * 8 + u) * HIDDEN + k4 * 4];
        #pragma unroll
        for (int kk = 0; kk < 4; ++kk) {
            float wv = sW[(k4 * 4 + kk) * HIDDEN + f];
            #pragma unroll
            for (int u = 0; u < 8; ++u) {
                const float* xp = (const float*)&xr[u];
                acc[u] = fmaf(xp[kk], wv, acc[u]);
            }
        }
    }
    #pragma unroll
    for (int u = 0; u < 8; ++u) {
        int n = base + wid * 8 + u;
        if (n < N_NODES) h[n * HIDDEN + f] = acc[u];
    }
}

// ---------------- attention score ----------------
__global__ void k_att(const float* __restrict__ agg2, const float* __restrict__ att_w,
                      const float* __restrict__ att_b, float* __restrict__ att_s) {
    int n = blockIdx.x * 4 + (threadIdx.x >> 6);
    int f = threadIdx.x & 63;
    float v = 0.0f;
    if (n < N_NODES) v = fmaxf(agg2[n * HIDDEN + f], 0.0f) * att_w[f];
    #pragma unroll
    for (int o = 32; o > 0; o >>= 1) v += __shfl_down(v, o, 64);
    if (f == 0 && n < N_NODES) {
        float s = v + att_b[0];
        att_s[n] = (s > 0.0f) ? s : LEAKY * s;
    }
}

// ---------------- graph boundaries (batch sorted) ----------------
__global__ void k_gbounds_init(int* gs, int* ge) {
    int i = blockIdx.x * 256 + threadIdx.x;
    if (i < N_GRAPHS) { gs[i] = 0; ge[i] = 0; }
}

__global__ void k_gbounds(const int* __restrict__ batch, int* gs, int* ge) {
    int n = blockIdx.x * 256 + threadIdx.x;
    if (n < N_NODES) {
        int b = batch[n];
        if (n == 0 || batch[n - 1] != b) gs[b] = n;
        if (n == N_NODES - 1 || batch[n + 1] != b) ge[b] = n + 1;
    }
}

// ---------------- pooled readout ----------------
__global__ __launch_bounds__(64) void k_pool(const float* __restrict__ agg2,
                                             const float* __restrict__ att_s,
                                             const int* __restrict__ gs,
                                             const int* __restrict__ ge,
                                             float* __restrict__ g) {
    int gid = blockIdx.x;
    int f = threadIdx.x;
    int s = gs[gid], e = ge[gid];

    float m = -INFINITY;
    for (int n = s + f; n < e; n += 64) m = fmaxf(m, att_s[n]);
    #pragma unroll
    for (int o = 32; o > 0; o >>= 1) m = fmaxf(m, __shfl_xor(m, o, 64));

    float z = 0.0f;
    for (int n = s + f; n < e; n += 64) z += expf(att_s[n] - m);
    #pragma unroll
    for (int o = 32; o > 0; o >>= 1) z += __shfl_xor(z, o, 64);

    float acc = 0.0f;
    if (e > s) {
        float inv = 1.0f / z;
        for (int n = s; n < e; ++n) {
            float w = expf(att_s[n] - m) * inv;
            acc = fmaf(w, fmaxf(agg2[n * HIDDEN + f], 0.0f), acc);
        }
    }
    g[gid * HIDDEN + f] = acc;
}

// ---------------- head MLPs ----------------
__global__ void k_mlp1(const float* __restrict__ g, const float* __restrict__ W,
                       const float* __restrict__ b, float* __restrict__ t1) {
    int idx = blockIdx.x * 256 + threadIdx.x;
    if (idx < N_GRAPHS * EMBED) {
        int r = idx / EMBED, c = idx - r * EMBED;
        float acc = b[c];
        #pragma unroll 8
        for (int k = 0; k < HIDDEN; ++k) acc = fmaf(g[r * HIDDEN + k], W[k * EMBED + c], acc);
        t1[idx] = acc;
    }
}

__global__ void k_mlp2(const float* __restrict__ t1, const float* __restrict__ W,
                       const float* __restrict__ b, float* __restrict__ t2) {
    int idx = blockIdx.x * 256 + threadIdx.x;
    if (idx < N_GRAPHS * 128) {
        int r = idx >> 7, c = idx & 127;
        float acc = b[c];
        for (int k = 0; k < EMBED; ++k) acc = fmaf(t1[r * EMBED + k], W[k * 128 + c], acc);
        t2[idx] = fmaxf(acc, 0.0f);
    }
}

__global__ void k_mlp3(const float* __restrict__ t2, const float* __restrict__ W,
                       const float* __restrict__ b, float* __restrict__ out) {
    int idx = blockIdx.x * 256 + threadIdx.x;
    if (idx < N_GRAPHS * N_CLASSES) {
        int r = idx / N_CLASSES, c = idx - r * N_CLASSES;
        float acc = b[c];
        #pragma unroll 8
        for (int k = 0; k < 128; ++k) acc = fmaf(t2[r * 128 + k], W[k * N_CLASSES + c], acc);
        out[idx] = acc;
    }
}

extern "C" void kernel_launch(void* const* d_in, const int* in_sizes, int n_in,
                              void* d_out, int out_size, void* d_ws, size_t ws_size,
                              hipStream_t stream) {
    const float* x      = (const float*)d_in[0];
    const int*   ei     = (const int*)d_in[1];
    const int*   batch  = (const int*)d_in[2];
    const float* W1     = (const float*)d_in[3];
    const float* b1     = (const float*)d_in[4];
    const float* W2     = (const float*)d_in[5];
    const float* b2     = (const float*)d_in[6];
    const float* att_w  = (const float*)d_in[7];
    const float* att_b  = (const float*)d_in[8];
    const float* proj_w = (const float*)d_in[9];
    const float* proj_b = (const float*)d_in[10];
    const float* cls_w1 = (const float*)d_in[11];
    const float* cls_b1 = (const float*)d_in[12];
    const float* cls_w2 = (const float*)d_in[13];
    const float* cls_b2 = (const float*)d_in[14];
    float* out = (float*)d_out;

    const int* e_src = ei;
    const int* e_dst = ei + N_EDGES;

    // workspace layout
    float* ws        = (float*)d_ws;
    float* dis       = ws;                         // 50048
    int*   deg_i     = (int*)(dis + 50048);        // 50048
    int*   cursor    = deg_i + 50048;              // 50048
    int*   row_start = cursor + 50048;             // 50056 (N+1, padded)
    int*   partials  = row_start + 50056;          // 256
    int*   col       = partials + 256;             // 800000
    float* nrm       = (float*)(col + 800000);     // 800000
    float* bufA      = nrm + 800000;               // 3.2M
    float* bufB      = bufA + N_NODES * HIDDEN;    // 3.2M
    float* att_s     = bufB + N_NODES * HIDDEN;    // 50048
    float* gbuf      = att_s + 50048;              // 500*64
    float* t1        = gbuf + N_GRAPHS * HIDDEN;   // 500*300
    float* t2        = t1 + N_GRAPHS * EMBED;      // 500*128
    int*   gs        = (int*)(t2 + N_GRAPHS * 128);
    int*   ge        = gs + N_GRAPHS;

    const int NB_N    = (N_NODES + 255) / 256;      // 196
    const int NB_E    = (N_EDGES + 255) / 256;      // 3125
    const int NB_ROW4 = (N_NODES + 3) / 4;          // 12500
    const int NB_G32  = (N_NODES + G1_ROWS - 1) / G1_ROWS;  // 1563

    // CSR build
    k_zero<<<NB_N, 256, 0, stream>>>(deg_i, cursor);
    k_deg<<<NB_E, 256, 0, stream>>>(e_dst, deg_i);
    k_scan1<<<SCAN_BLOCKS, 256, 0, stream>>>(deg_i, row_start, partials, dis);
    k_scan2<<<1, 256, 0, stream>>>(partials);
    k_scan3<<<SCAN_BLOCKS, 256, 0, stream>>>(row_start, partials);
    k_fill<<<NB_E, 256, 0, stream>>>(e_src, e_dst, dis, row_start, cursor, col, nrm);

    // conv1
    k_gemm1<<<NB_G32, 256, 0, stream>>>(x, W1, bufA);
    k_gather<<<NB_ROW4, 256, 0, stream>>>(bufA, col, nrm, row_start, dis, b1, bufB);

    // conv2 (relu fused into gemm2 load)
    k_gemm2<<<NB_G32, 256, 0, stream>>>(bufB, W2, bufA);
    k_gather<<<NB_ROW4, 256, 0, stream>>>(bufA, col, nrm, row_start, dis, b2, bufB);

    // attention + pooling
    k_att<<<NB_ROW4, 256, 0, stream>>>(bufB, att_w, att_b, att_s);
    k_gbounds_init<<<(N_GRAPHS + 255) / 256, 256, 0, stream>>>(gs, ge);
    k_gbounds<<<NB_N, 256, 0, stream>>>(batch, gs, ge);
    k_pool<<<N_GRAPHS, 64, 0, stream>>>(bufB, att_s, gs, ge, gbuf);

    // head
    k_mlp1<<<(N_GRAPHS * EMBED + 255) / 256, 256, 0, stream>>>(gbuf, proj_w, proj_b, t1);
    k_mlp2<<<(N_GRAPHS * 128 + 255) / 256, 256, 0, stream>>>(t1, cls_w1, cls_b1, t2);
    k_mlp3<<<(N_GRAPHS * N_CLASSES + 255) / 256, 256, 0, stream>>>(t2, cls_w2, cls_b2, out);
}

// Round 3
// 288.876 us; speedup vs baseline: 1.9648x; 1.2066x over previous
//
#include <hip/hip_runtime.h>
#include <math.h>

#define N_NODES   50000
#define N_EDGES   800000
#define N_FEAT    128
#define HIDDEN    64
#define EMBED     300
#define N_CLASSES 10
#define N_GRAPHS  500
#define LEAKY     0.01f
#define SCAN_BLOCKS ((N_NODES + 255) / 256)  // 196
#define G1_ROWS   32

// ---------------- CSR build ----------------
__global__ void k_zero(int* deg, int* cursor) {
    int i = blockIdx.x * 256 + threadIdx.x;
    if (i < N_NODES) { deg[i] = 0; cursor[i] = 0; }
}

__global__ void k_deg(const int* __restrict__ dst, int* deg) {
    int e = blockIdx.x * 256 + threadIdx.x;
    if (e < N_EDGES) atomicAdd(&deg[dst[e]], 1);
}

__global__ __launch_bounds__(256) void k_scan1(const int* __restrict__ deg, int* row_start,
                                               int* partials, float* dis) {
    __shared__ int wsum[4];
    int i = blockIdx.x * 256 + threadIdx.x;
    int v = (i < N_NODES) ? deg[i] : 0;
    int lane = threadIdx.x & 63, wid = threadIdx.x >> 6;
    int s = v;
    #pragma unroll
    for (int off = 1; off < 64; off <<= 1) {
        int t = __shfl_up(s, off, 64);
        if (lane >= off) s += t;
    }
    if (lane == 63) wsum[wid] = s;
    __syncthreads();
    int woff = 0;
    for (int w = 0; w < wid; ++w) woff += wsum[w];
    if (i < N_NODES) {
        row_start[i] = woff + s - v;
        dis[i] = rsqrtf((float)(deg[i] + 1));
    }
    if (threadIdx.x == 255) partials[blockIdx.x] = woff + s;
}

__global__ __launch_bounds__(256) void k_scan2(int* partials) {
    __shared__ int wsum[4];
    int v = (threadIdx.x < SCAN_BLOCKS) ? partials[threadIdx.x] : 0;
    int lane = threadIdx.x & 63, wid = threadIdx.x >> 6;
    int s = v;
    #pragma unroll
    for (int off = 1; off < 64; off <<= 1) {
        int t = __shfl_up(s, off, 64);
        if (lane >= off) s += t;
    }
    if (lane == 63) wsum[wid] = s;
    __syncthreads();
    int woff = 0;
    for (int w = 0; w < wid; ++w) woff += wsum[w];
    if (threadIdx.x < SCAN_BLOCKS) partials[threadIdx.x] = woff + s - v;
}

__global__ void k_scan3(int* row_start, const int* __restrict__ partials) {
    int i = blockIdx.x * 256 + threadIdx.x;
    if (i < N_NODES) row_start[i] += partials[blockIdx.x];
    if (i == 0) row_start[N_NODES] = N_EDGES;
}

__global__ void k_fill(const int* __restrict__ src, const int* __restrict__ dst,
                       const float* __restrict__ dis, const int* __restrict__ row_start,
                       int* cursor, int* col, float* nrm) {
    int e = blockIdx.x * 256 + threadIdx.x;
    if (e < N_EDGES) {
        int s = src[e], d = dst[e];
        int pos = row_start[d] + atomicAdd(&cursor[d], 1);
        col[pos] = s;
        nrm[pos] = dis[s] * dis[d];
    }
}

// ---------------- GEMM1: h = x @ W1  (50000x128 @ 128x64), 32 rows/block ----------------
__global__ __launch_bounds__(256) void k_gemm1(const float* __restrict__ x,
                                               const float* __restrict__ W,
                                               float* __restrict__ h) {
    __shared__ float sW[N_FEAT * HIDDEN];   // 32 KB, [k][f]
    __shared__ float sx[G1_ROWS * N_FEAT];  // 16 KB, [r][k]
    {
        const float4* W4 = (const float4*)W;
        float4* sW4 = (float4*)sW;
        #pragma unroll
        for (int i = 0; i < N_FEAT * HIDDEN / 4 / 256; ++i)
            sW4[i * 256 + threadIdx.x] = W4[i * 256 + threadIdx.x];

        int base = blockIdx.x * G1_ROWS;
        const float4* x4 = (const float4*)(x + (size_t)base * N_FEAT);
        float4* sx4 = (float4*)sx;
        int lim = (N_NODES - base) * (N_FEAT / 4);
        #pragma unroll
        for (int i = 0; i < G1_ROWS * N_FEAT / 4 / 256; ++i) {
            int idx = i * 256 + threadIdx.x;
            sx4[idx] = (idx < lim) ? x4[idx] : make_float4(0.f, 0.f, 0.f, 0.f);
        }
    }
    __syncthreads();

    int f = threadIdx.x & 63, wid = threadIdx.x >> 6;
    float acc[8];
    #pragma unroll
    for (int u = 0; u < 8; ++u) acc[u] = 0.0f;

    const float4* sx4 = (const float4*)sx;
    #pragma unroll 4
    for (int k4 = 0; k4 < N_FEAT / 4; ++k4) {
        float w0 = sW[(k4 * 4 + 0) * HIDDEN + f];
        float w1 = sW[(k4 * 4 + 1) * HIDDEN + f];
        float w2 = sW[(k4 * 4 + 2) * HIDDEN + f];
        float w3 = sW[(k4 * 4 + 3) * HIDDEN + f];
        #pragma unroll
        for (int u = 0; u < 8; ++u) {
            float4 xv = sx4[(wid * 8 + u) * (N_FEAT / 4) + k4];
            acc[u] = fmaf(xv.x, w0, fmaf(xv.y, w1, fmaf(xv.z, w2, fmaf(xv.w, w3, acc[u]))));
        }
    }
    int base = blockIdx.x * G1_ROWS;
    #pragma unroll
    for (int u = 0; u < 8; ++u) {
        int n = base + wid * 8 + u;
        if (n < N_NODES) h[n * HIDDEN + f] = acc[u];
    }
}

// ---------------- GEMM2: h2 = relu(agg1) @ W2  (50000x64 @ 64x64) ----------------
__global__ __launch_bounds__(256) void k_gemm2(const float* __restrict__ a,
                                               const float* __restrict__ W,
                                               float* __restrict__ h) {
    __shared__ float sW[HIDDEN * HIDDEN];   // 16 KB
    __shared__ float sa[G1_ROWS * HIDDEN];  // 8 KB
    {
        const float4* W4 = (const float4*)W;
        float4* sW4 = (float4*)sW;
        #pragma unroll
        for (int i = 0; i < HIDDEN * HIDDEN / 4 / 256; ++i)
            sW4[i * 256 + threadIdx.x] = W4[i * 256 + threadIdx.x];

        int base = blockIdx.x * G1_ROWS;
        const float4* a4 = (const float4*)(a + (size_t)base * HIDDEN);
        float4* sa4 = (float4*)sa;
        int lim = (N_NODES - base) * (HIDDEN / 4);
        #pragma unroll
        for (int i = 0; i < G1_ROWS * HIDDEN / 4 / 256; ++i) {
            int idx = i * 256 + threadIdx.x;
            float4 v = (idx < lim) ? a4[idx] : make_float4(0.f, 0.f, 0.f, 0.f);
            v.x = fmaxf(v.x, 0.f); v.y = fmaxf(v.y, 0.f);
            v.z = fmaxf(v.z, 0.f); v.w = fmaxf(v.w, 0.f);
            sa4[idx] = v;
        }
    }
    __syncthreads();

    int f = threadIdx.x & 63, wid = threadIdx.x >> 6;
    float acc[8];
    #pragma unroll
    for (int u = 0; u < 8; ++u) acc[u] = 0.0f;

    const float4* sa4 = (const float4*)sa;
    #pragma unroll 4
    for (int k4 = 0; k4 < HIDDEN / 4; ++k4) {
        float w0 = sW[(k4 * 4 + 0) * HIDDEN + f];
        float w1 = sW[(k4 * 4 + 1) * HIDDEN + f];
        float w2 = sW[(k4 * 4 + 2) * HIDDEN + f];
        float w3 = sW[(k4 * 4 + 3) * HIDDEN + f];
        #pragma unroll
        for (int u = 0; u < 8; ++u) {
            float4 xv = sa4[(wid * 8 + u) * (HIDDEN / 4) + k4];
            acc[u] = fmaf(xv.x, w0, fmaf(xv.y, w1, fmaf(xv.z, w2, fmaf(xv.w, w3, acc[u]))));
        }
    }
    int base = blockIdx.x * G1_ROWS;
    #pragma unroll
    for (int u = 0; u < 8; ++u) {
        int n = base + wid * 8 + u;
        if (n < N_NODES) h[n * HIDDEN + f] = acc[u];
    }
}

// ---------------- fused gather: agg = relu(sum_j nrm*h[col] + h*dis^2 + b); optional att ----------------
template<bool FUSE_ATT>
__global__ __launch_bounds__(256) void k_gather(const float* __restrict__ h,
                                                const int* __restrict__ col,
                                                const float* __restrict__ nrm,
                                                const int* __restrict__ row_start,
                                                const float* __restrict__ dis,
                                                const float* __restrict__ b,
                                                float* __restrict__ agg,
                                                const float* __restrict__ att_w,
                                                const float* __restrict__ att_b,
                                                float* __restrict__ att_s) {
    int node = blockIdx.x * 4 + (threadIdx.x >> 6);
    if (node >= N_NODES) return;
    int f = threadIdx.x & 63;
    int s = row_start[node], e = row_start[node + 1];
    float dv = dis[node];
    float acc0 = fmaf(h[node * HIDDEN + f], dv * dv, b[f]);
    float acc1 = 0.0f;
    int j = s;
    for (; j + 1 < e; j += 2) {
        int c0 = col[j], c1 = col[j + 1];
        float w0 = nrm[j], w1 = nrm[j + 1];
        acc0 = fmaf(w0, h[c0 * HIDDEN + f], acc0);
        acc1 = fmaf(w1, h[c1 * HIDDEN + f], acc1);
    }
    if (j < e) acc0 = fmaf(nrm[j], h[col[j] * HIDDEN + f], acc0);
    float r = fmaxf(acc0 + acc1, 0.0f);   // fused ReLU (downstream always consumes relu'd)
    agg[node * HIDDEN + f] = r;
    if (FUSE_ATT) {
        float v = r * att_w[f];
        #pragma unroll
        for (int o = 32; o > 0; o >>= 1) v += __shfl_down(v, o, 64);
        if (f == 0) {
            float sc = v + att_b[0];
            att_s[node] = (sc > 0.0f) ? sc : LEAKY * sc;
        }
    }
}

// ---------------- graph boundaries (batch sorted) ----------------
__global__ void k_gbounds_init(int* gs, int* ge) {
    int i = blockIdx.x * 256 + threadIdx.x;
    if (i < N_GRAPHS) { gs[i] = 0; ge[i] = 0; }
}

__global__ void k_gbounds(const int* __restrict__ batch, int* gs, int* ge) {
    int n = blockIdx.x * 256 + threadIdx.x;
    if (n < N_NODES) {
        int b = batch[n];
        if (n == 0 || batch[n - 1] != b) gs[b] = n;
        if (n == N_NODES - 1 || batch[n + 1] != b) ge[b] = n + 1;
    }
}

// ---------------- pooled readout (agg2 already relu'd), 4 waves/graph ----------------
__global__ __launch_bounds__(256) void k_pool(const float* __restrict__ agg2,
                                              const float* __restrict__ att_s,
                                              const int* __restrict__ gs,
                                              const int* __restrict__ ge,
                                              float* __restrict__ g) {
    __shared__ float red[4];
    __shared__ float red2[4 * 64];
    int gid = blockIdx.x;
    int tid = threadIdx.x, f = tid & 63, w = tid >> 6;
    int s = gs[gid], e = ge[gid];

    // max
    float m = -INFINITY;
    for (int n = s + tid; n < e; n += 256) m = fmaxf(m, att_s[n]);
    #pragma unroll
    for (int o = 32; o > 0; o >>= 1) m = fmaxf(m, __shfl_xor(m, o, 64));
    if (f == 0) red[w] = m;
    __syncthreads();
    m = fmaxf(fmaxf(red[0], red[1]), fmaxf(red[2], red[3]));
    __syncthreads();

    // denom
    float z = 0.0f;
    for (int n = s + tid; n < e; n += 256) z += expf(att_s[n] - m);
    #pragma unroll
    for (int o = 32; o > 0; o >>= 1) z += __shfl_xor(z, o, 64);
    if (f == 0) red[w] = z;
    __syncthreads();
    z = red[0] + red[1] + red[2] + red[3];
    float inv = (e > s) ? 1.0f / z : 0.0f;

    // weighted sum, wave w takes nodes s+w, s+w+4, ...
    float acc = 0.0f;
    for (int n = s + w; n < e; n += 4) {
        float wt = expf(att_s[n] - m) * inv;
        acc = fmaf(wt, agg2[n * HIDDEN + f], acc);
    }
    red2[w * 64 + f] = acc;
    __syncthreads();
    if (w == 0)
        g[gid * HIDDEN + f] = red2[f] + red2[64 + f] + red2[128 + f] + red2[192 + f];
}

// ---------------- head MLPs ----------------
__global__ void k_mlp1(const float* __restrict__ g, const float* __restrict__ W,
                       const float* __restrict__ b, float* __restrict__ t1) {
    int idx = blockIdx.x * 256 + threadIdx.x;
    if (idx < N_GRAPHS * EMBED) {
        int r = idx / EMBED, c = idx - r * EMBED;
        float acc = b[c];
        #pragma unroll 8
        for (int k = 0; k < HIDDEN; ++k) acc = fmaf(g[r * HIDDEN + k], W[k * EMBED + c], acc);
        t1[idx] = acc;
    }
}

__global__ void k_mlp2(const float* __restrict__ t1, const float* __restrict__ W,
                       const float* __restrict__ b, float* __restrict__ t2) {
    int idx = blockIdx.x * 256 + threadIdx.x;
    if (idx < N_GRAPHS * 128) {
        int r = idx >> 7, c = idx & 127;
        float acc = b[c];
        for (int k = 0; k < EMBED; ++k) acc = fmaf(t1[r * EMBED + k], W[k * 128 + c], acc);
        t2[idx] = fmaxf(acc, 0.0f);
    }
}

__global__ void k_mlp3(const float* __restrict__ t2, const float* __restrict__ W,
                       const float* __restrict__ b, float* __restrict__ out) {
    int idx = blockIdx.x * 256 + threadIdx.x;
    if (idx < N_GRAPHS * N_CLASSES) {
        int r = idx / N_CLASSES, c = idx - r * N_CLASSES;
        float acc = b[c];
        #pragma unroll 8
        for (int k = 0; k < 128; ++k) acc = fmaf(t2[r * 128 + k], W[k * N_CLASSES + c], acc);
        out[idx] = acc;
    }
}

extern "C" void kernel_launch(void* const* d_in, const int* in_sizes, int n_in,
                              void* d_out, int out_size, void* d_ws, size_t ws_size,
                              hipStream_t stream) {
    const float* x      = (const float*)d_in[0];
    const int*   ei     = (const int*)d_in[1];
    const int*   batch  = (const int*)d_in[2];
    const float* W1     = (const float*)d_in[3];
    const float* b1     = (const float*)d_in[4];
    const float* W2     = (const float*)d_in[5];
    const float* b2     = (const float*)d_in[6];
    const float* att_w  = (const float*)d_in[7];
    const float* att_b  = (const float*)d_in[8];
    const float* proj_w = (const float*)d_in[9];
    const float* proj_b = (const float*)d_in[10];
    const float* cls_w1 = (const float*)d_in[11];
    const float* cls_b1 = (const float*)d_in[12];
    const float* cls_w2 = (const float*)d_in[13];
    const float* cls_b2 = (const float*)d_in[14];
    float* out = (float*)d_out;

    const int* e_src = ei;
    const int* e_dst = ei + N_EDGES;

    // workspace layout
    float* ws        = (float*)d_ws;
    float* dis       = ws;
    int*   deg_i     = (int*)(dis + 50048);
    int*   cursor    = deg_i + 50048;
    int*   row_start = cursor + 50048;
    int*   partials  = row_start + 50056;
    int*   col       = partials + 256;
    float* nrm       = (float*)(col + 800000);
    float* bufA      = nrm + 800000;
    float* bufB      = bufA + N_NODES * HIDDEN;
    float* att_s     = bufB + N_NODES * HIDDEN;
    float* gbuf      = att_s + 50048;
    float* t1        = gbuf + N_GRAPHS * HIDDEN;
    float* t2        = t1 + N_GRAPHS * EMBED;
    int*   gs        = (int*)(t2 + N_GRAPHS * 128);
    int*   ge        = gs + N_GRAPHS;

    const int NB_N    = (N_NODES + 255) / 256;
    const int NB_E    = (N_EDGES + 255) / 256;
    const int NB_ROW4 = (N_NODES + 3) / 4;
    const int NB_G32  = (N_NODES + G1_ROWS - 1) / G1_ROWS;

    // CSR build
    k_zero<<<NB_N, 256, 0, stream>>>(deg_i, cursor);
    k_deg<<<NB_E, 256, 0, stream>>>(e_dst, deg_i);
    k_scan1<<<SCAN_BLOCKS, 256, 0, stream>>>(deg_i, row_start, partials, dis);
    k_scan2<<<1, 256, 0, stream>>>(partials);
    k_scan3<<<SCAN_BLOCKS, 256, 0, stream>>>(row_start, partials);
    k_fill<<<NB_E, 256, 0, stream>>>(e_src, e_dst, dis, row_start, cursor, col, nrm);

    // conv1 (gather writes relu'd agg1)
    k_gemm1<<<NB_G32, 256, 0, stream>>>(x, W1, bufA);
    k_gather<false><<<NB_ROW4, 256, 0, stream>>>(bufA, col, nrm, row_start, dis, b1, bufB,
                                                 nullptr, nullptr, nullptr);

    // conv2 (gather writes relu'd agg2 + fused attention score)
    k_gemm2<<<NB_G32, 256, 0, stream>>>(bufB, W2, bufA);
    k_gather<true><<<NB_ROW4, 256, 0, stream>>>(bufA, col, nrm, row_start, dis, b2, bufB,
                                                att_w, att_b, att_s);

    // pooling
    k_gbounds_init<<<(N_GRAPHS + 255) / 256, 256, 0, stream>>>(gs, ge);
    k_gbounds<<<NB_N, 256, 0, stream>>>(batch, gs, ge);
    k_pool<<<N_GRAPHS, 256, 0, stream>>>(bufB, att_s, gs, ge, gbuf);

    // head
    k_mlp1<<<(N_GRAPHS * EMBED + 255) / 256, 256, 0, stream>>>(gbuf, proj_w, proj_b, t1);
    k_mlp2<<<(N_GRAPHS * 128 + 255) / 256, 256, 0, stream>>>(t1, cls_w1, cls_b1, t2);
    k_mlp3<<<(N_GRAPHS * N_CLASSES + 255) / 256, 256, 0, stream>>>(t2, cls_w2, cls_b2, out);
}

// Round 4
// 215.963 us; speedup vs baseline: 2.6281x; 1.3376x over previous
//
#include <hip/hip_runtime.h>
#include <hip/hip_fp16.h>
#include <math.h>

#define N_NODES   50000
#define N_EDGES   800000
#define N_FEAT    128
#define HIDDEN    64
#define EMBED     300
#define N_CLASSES 10
#define N_GRAPHS  500
#define LEAKY     0.01f
#define SCAN_BLOCKS ((N_NODES + 255) / 256)  // 196
#define G1_ROWS   32

// packed edge: low 16 bits = src node id (50000 < 65536), high 16 = fp16 norm
__device__ __forceinline__ float pk_w(unsigned p) {
    return __half2float(__ushort_as_half((unsigned short)(p >> 16)));
}
__device__ __forceinline__ int pk_c(unsigned p) { return (int)(p & 0xFFFFu); }

// ---------------- init: deg = 0, gs/ge = 0 ----------------
__global__ void k_zero(int* deg, int* gs, int* ge) {
    int i = blockIdx.x * 256 + threadIdx.x;
    if (i < N_NODES) deg[i] = 0;
    if (i < N_GRAPHS) { gs[i] = 0; ge[i] = 0; }
}

// ---------------- degree count + per-edge rank (coalesced) ----------------
__global__ void k_deg_rank(const int* __restrict__ dst, int* deg, int* rank) {
    int e = blockIdx.x * 256 + threadIdx.x;
    if (e < N_EDGES) rank[e] = atomicAdd(&deg[dst[e]], 1);
}

// ---------------- scan: deg -> row_start (exclusive); dis = rsqrt(deg+1) ----------------
__global__ __launch_bounds__(256) void k_scan1(const int* __restrict__ deg, int* row_start,
                                               int* partials, float* dis) {
    __shared__ int wsum[4];
    int i = blockIdx.x * 256 + threadIdx.x;
    int v = (i < N_NODES) ? deg[i] : 0;
    int lane = threadIdx.x & 63, wid = threadIdx.x >> 6;
    int s = v;
    #pragma unroll
    for (int off = 1; off < 64; off <<= 1) {
        int t = __shfl_up(s, off, 64);
        if (lane >= off) s += t;
    }
    if (lane == 63) wsum[wid] = s;
    __syncthreads();
    int woff = 0;
    for (int w = 0; w < wid; ++w) woff += wsum[w];
    if (i < N_NODES) {
        row_start[i] = woff + s - v;
        dis[i] = rsqrtf((float)(deg[i] + 1));
    }
    if (threadIdx.x == 255) partials[blockIdx.x] = woff + s;
}

__global__ __launch_bounds__(256) void k_scan2(int* partials) {
    __shared__ int wsum[4];
    int v = (threadIdx.x < SCAN_BLOCKS) ? partials[threadIdx.x] : 0;
    int lane = threadIdx.x & 63, wid = threadIdx.x >> 6;
    int s = v;
    #pragma unroll
    for (int off = 1; off < 64; off <<= 1) {
        int t = __shfl_up(s, off, 64);
        if (lane >= off) s += t;
    }
    if (lane == 63) wsum[wid] = s;
    __syncthreads();
    int woff = 0;
    for (int w = 0; w < wid; ++w) woff += wsum[w];
    if (threadIdx.x < SCAN_BLOCKS) partials[threadIdx.x] = woff + s - v;
}

__global__ void k_scan3(int* row_start, const int* __restrict__ partials) {
    int i = blockIdx.x * 256 + threadIdx.x;
    if (i < N_NODES) row_start[i] += partials[blockIdx.x];
    if (i == 0) row_start[N_NODES] = N_EDGES;
}

// ---------------- CSR fill: one packed 4B scatter per edge ----------------
__global__ void k_fill(const int* __restrict__ src, const int* __restrict__ dst,
                       const int* __restrict__ rank, const int* __restrict__ row_start,
                       const float* __restrict__ dis, unsigned* __restrict__ pk) {
    int e = blockIdx.x * 256 + threadIdx.x;
    if (e < N_EDGES) {
        int s = src[e], d = dst[e];
        float w = dis[s] * dis[d];
        unsigned short wh = __half_as_ushort(__float2half(w));
        pk[row_start[d] + rank[e]] = (unsigned)s | ((unsigned)wh << 16);
    }
}

// ---------------- GEMM1: h1 = x @ W1 (fp16 out), 32 rows/block ----------------
__global__ __launch_bounds__(256) void k_gemm1(const float* __restrict__ x,
                                               const float* __restrict__ W,
                                               __half* __restrict__ h) {
    __shared__ float sW[N_FEAT * HIDDEN];   // 32 KB
    __shared__ float sx[G1_ROWS * N_FEAT];  // 16 KB
    {
        const float4* W4 = (const float4*)W;
        float4* sW4 = (float4*)sW;
        #pragma unroll
        for (int i = 0; i < N_FEAT * HIDDEN / 4 / 256; ++i)
            sW4[i * 256 + threadIdx.x] = W4[i * 256 + threadIdx.x];

        int base = blockIdx.x * G1_ROWS;
        const float4* x4 = (const float4*)(x + (size_t)base * N_FEAT);
        float4* sx4 = (float4*)sx;
        int lim = (N_NODES - base) * (N_FEAT / 4);
        #pragma unroll
        for (int i = 0; i < G1_ROWS * N_FEAT / 4 / 256; ++i) {
            int idx = i * 256 + threadIdx.x;
            sx4[idx] = (idx < lim) ? x4[idx] : make_float4(0.f, 0.f, 0.f, 0.f);
        }
    }
    __syncthreads();

    int f = threadIdx.x & 63, wid = threadIdx.x >> 6;
    float acc[8];
    #pragma unroll
    for (int u = 0; u < 8; ++u) acc[u] = 0.0f;

    const float4* sx4 = (const float4*)sx;
    #pragma unroll 4
    for (int k4 = 0; k4 < N_FEAT / 4; ++k4) {
        float w0 = sW[(k4 * 4 + 0) * HIDDEN + f];
        float w1 = sW[(k4 * 4 + 1) * HIDDEN + f];
        float w2 = sW[(k4 * 4 + 2) * HIDDEN + f];
        float w3 = sW[(k4 * 4 + 3) * HIDDEN + f];
        #pragma unroll
        for (int u = 0; u < 8; ++u) {
            float4 xv = sx4[(wid * 8 + u) * (N_FEAT / 4) + k4];
            acc[u] = fmaf(xv.x, w0, fmaf(xv.y, w1, fmaf(xv.z, w2, fmaf(xv.w, w3, acc[u]))));
        }
    }
    int base = blockIdx.x * G1_ROWS;
    #pragma unroll
    for (int u = 0; u < 8; ++u) {
        int n = base + wid * 8 + u;
        if (n < N_NODES) h[(size_t)n * HIDDEN + f] = __float2half(acc[u]);
    }
}

// ---------------- fused conv1-gather + gemm2: h2 = relu(agg1) @ W2 (fp16 out) ----------------
// grid is exactly N_NODES/4 blocks: no bounds check, barrier is uniform.
__global__ __launch_bounds__(256) void k_gg(const __half* __restrict__ h1,
                                            const unsigned* __restrict__ pk,
                                            const int* __restrict__ row_start,
                                            const float* __restrict__ dis,
                                            const float* __restrict__ b1,
                                            const float* __restrict__ W2,
                                            __half* __restrict__ h2) {
    __shared__ float sW[HIDDEN * HIDDEN];  // 16 KB
    __shared__ float sa[4 * HIDDEN];       // 1 KB
    {
        const float4* W4 = (const float4*)W2;
        float4* sW4 = (float4*)sW;
        #pragma unroll
        for (int i = 0; i < 4; ++i)
            sW4[i * 256 + threadIdx.x] = W4[i * 256 + threadIdx.x];
    }

    int wid = threadIdx.x >> 6, f = threadIdx.x & 63;
    int node = blockIdx.x * 4 + wid;
    int s = row_start[node], e = row_start[node + 1];
    float dv = dis[node];
    float a0 = fmaf(__half2float(h1[(size_t)node * HIDDEN + f]), dv * dv, b1[f]);
    float a1 = 0.f, a2 = 0.f, a3 = 0.f;
    int j = s;
    for (; j + 3 < e; j += 4) {
        unsigned p0 = pk[j], p1 = pk[j + 1], p2 = pk[j + 2], p3 = pk[j + 3];
        a0 = fmaf(pk_w(p0), __half2float(h1[(size_t)pk_c(p0) * HIDDEN + f]), a0);
        a1 = fmaf(pk_w(p1), __half2float(h1[(size_t)pk_c(p1) * HIDDEN + f]), a1);
        a2 = fmaf(pk_w(p2), __half2float(h1[(size_t)pk_c(p2) * HIDDEN + f]), a2);
        a3 = fmaf(pk_w(p3), __half2float(h1[(size_t)pk_c(p3) * HIDDEN + f]), a3);
    }
    for (; j < e; ++j) {
        unsigned p = pk[j];
        a0 = fmaf(pk_w(p), __half2float(h1[(size_t)pk_c(p) * HIDDEN + f]), a0);
    }
    float r = fmaxf((a0 + a1) + (a2 + a3), 0.f);

    sa[wid * HIDDEN + f] = r;
    __syncthreads();

    float o = 0.f;
    #pragma unroll
    for (int k = 0; k < HIDDEN; ++k)
        o = fmaf(sa[wid * HIDDEN + k], sW[k * HIDDEN + f], o);
    h2[(size_t)node * HIDDEN + f] = __float2half(o);
}

// ---------------- conv2-gather + fused attention score ----------------
__global__ __launch_bounds__(256) void k_gather2(const __half* __restrict__ h2,
                                                 const unsigned* __restrict__ pk,
                                                 const int* __restrict__ row_start,
                                                 const float* __restrict__ dis,
                                                 const float* __restrict__ b2,
                                                 const float* __restrict__ att_w,
                                                 const float* __restrict__ att_b,
                                                 float* __restrict__ agg2,
                                                 float* __restrict__ att_s) {
    int wid = threadIdx.x >> 6, f = threadIdx.x & 63;
    int node = blockIdx.x * 4 + wid;
    if (node >= N_NODES) return;
    int s = row_start[node], e = row_start[node + 1];
    float dv = dis[node];
    float a0 = fmaf(__half2float(h2[(size_t)node * HIDDEN + f]), dv * dv, b2[f]);
    float a1 = 0.f, a2 = 0.f, a3 = 0.f;
    int j = s;
    for (; j + 3 < e; j += 4) {
        unsigned p0 = pk[j], p1 = pk[j + 1], p2 = pk[j + 2], p3 = pk[j + 3];
        a0 = fmaf(pk_w(p0), __half2float(h2[(size_t)pk_c(p0) * HIDDEN + f]), a0);
        a1 = fmaf(pk_w(p1), __half2float(h2[(size_t)pk_c(p1) * HIDDEN + f]), a1);
        a2 = fmaf(pk_w(p2), __half2float(h2[(size_t)pk_c(p2) * HIDDEN + f]), a2);
        a3 = fmaf(pk_w(p3), __half2float(h2[(size_t)pk_c(p3) * HIDDEN + f]), a3);
    }
    for (; j < e; ++j) {
        unsigned p = pk[j];
        a0 = fmaf(pk_w(p), __half2float(h2[(size_t)pk_c(p) * HIDDEN + f]), a0);
    }
    float r = fmaxf((a0 + a1) + (a2 + a3), 0.f);
    agg2[(size_t)node * HIDDEN + f] = r;

    float v = r * att_w[f];
    #pragma unroll
    for (int o = 32; o > 0; o >>= 1) v += __shfl_down(v, o, 64);
    if (f == 0) {
        float sc = v + att_b[0];
        att_s[node] = (sc > 0.0f) ? sc : LEAKY * sc;
    }
}

// ---------------- graph boundaries (batch sorted) ----------------
__global__ void k_gbounds(const int* __restrict__ batch, int* gs, int* ge) {
    int n = blockIdx.x * 256 + threadIdx.x;
    if (n < N_NODES) {
        int b = batch[n];
        if (n == 0 || batch[n - 1] != b) gs[b] = n;
        if (n == N_NODES - 1 || batch[n + 1] != b) ge[b] = n + 1;
    }
}

// ---------------- pooled readout, 4 waves/graph ----------------
__global__ __launch_bounds__(256) void k_pool(const float* __restrict__ agg2,
                                              const float* __restrict__ att_s,
                                              const int* __restrict__ gs,
                                              const int* __restrict__ ge,
                                              float* __restrict__ g) {
    __shared__ float red[4];
    __shared__ float red2[4 * 64];
    int gid = blockIdx.x;
    int tid = threadIdx.x, f = tid & 63, w = tid >> 6;
    int s = gs[gid], e = ge[gid];

    float m = -INFINITY;
    for (int n = s + tid; n < e; n += 256) m = fmaxf(m, att_s[n]);
    #pragma unroll
    for (int o = 32; o > 0; o >>= 1) m = fmaxf(m, __shfl_xor(m, o, 64));
    if (f == 0) red[w] = m;
    __syncthreads();
    m = fmaxf(fmaxf(red[0], red[1]), fmaxf(red[2], red[3]));
    __syncthreads();

    float z = 0.0f;
    for (int n = s + tid; n < e; n += 256) z += expf(att_s[n] - m);
    #pragma unroll
    for (int o = 32; o > 0; o >>= 1) z += __shfl_xor(z, o, 64);
    if (f == 0) red[w] = z;
    __syncthreads();
    z = red[0] + red[1] + red[2] + red[3];
    float inv = (e > s) ? 1.0f / z : 0.0f;

    float acc = 0.0f;
    for (int n = s + w; n < e; n += 4) {
        float wt = expf(att_s[n] - m) * inv;
        acc = fmaf(wt, agg2[(size_t)n * HIDDEN + f], acc);
    }
    red2[w * 64 + f] = acc;
    __syncthreads();
    if (w == 0)
        g[gid * HIDDEN + f] = red2[f] + red2[64 + f] + red2[128 + f] + red2[192 + f];
}

// ---------------- head MLPs ----------------
__global__ void k_mlp1(const float* __restrict__ g, const float* __restrict__ W,
                       const float* __restrict__ b, float* __restrict__ t1) {
    int idx = blockIdx.x * 256 + threadIdx.x;
    if (idx < N_GRAPHS * EMBED) {
        int r = idx / EMBED, c = idx - r * EMBED;
        float acc = b[c];
        #pragma unroll 8
        for (int k = 0; k < HIDDEN; ++k) acc = fmaf(g[r * HIDDEN + k], W[k * EMBED + c], acc);
        t1[idx] = acc;
    }
}

__global__ void k_mlp2(const float* __restrict__ t1, const float* __restrict__ W,
                       const float* __restrict__ b, float* __restrict__ t2) {
    int idx = blockIdx.x * 256 + threadIdx.x;
    if (idx < N_GRAPHS * 128) {
        int r = idx >> 7, c = idx & 127;
        float acc = b[c];
        for (int k = 0; k < EMBED; ++k) acc = fmaf(t1[r * EMBED + k], W[k * 128 + c], acc);
        t2[idx] = fmaxf(acc, 0.0f);
    }
}

__global__ void k_mlp3(const float* __restrict__ t2, const float* __restrict__ W,
                       const float* __restrict__ b, float* __restrict__ out) {
    int idx = blockIdx.x * 256 + threadIdx.x;
    if (idx < N_GRAPHS * N_CLASSES) {
        int r = idx / N_CLASSES, c = idx - r * N_CLASSES;
        float acc = b[c];
        #pragma unroll 8
        for (int k = 0; k < 128; ++k) acc = fmaf(t2[r * 128 + k], W[k * N_CLASSES + c], acc);
        out[idx] = acc;
    }
}

extern "C" void kernel_launch(void* const* d_in, const int* in_sizes, int n_in,
                              void* d_out, int out_size, void* d_ws, size_t ws_size,
                              hipStream_t stream) {
    const float* x      = (const float*)d_in[0];
    const int*   ei     = (const int*)d_in[1];
    const int*   batch  = (const int*)d_in[2];
    const float* W1     = (const float*)d_in[3];
    const float* b1     = (const float*)d_in[4];
    const float* W2     = (const float*)d_in[5];
    const float* b2     = (const float*)d_in[6];
    const float* att_w  = (const float*)d_in[7];
    const float* att_b  = (const float*)d_in[8];
    const float* proj_w = (const float*)d_in[9];
    const float* proj_b = (const float*)d_in[10];
    const float* cls_w1 = (const float*)d_in[11];
    const float* cls_b1 = (const float*)d_in[12];
    const float* cls_w2 = (const float*)d_in[13];
    const float* cls_b2 = (const float*)d_in[14];
    float* out = (float*)d_out;

    const int* e_src = ei;
    const int* e_dst = ei + N_EDGES;

    // workspace layout (4B words)
    float* base = (float*)d_ws;
    size_t o = 0;
    float*    dis       = base + o;          o += 50048;
    int*      deg_i     = (int*)(base + o);  o += 50048;
    int*      row_start = (int*)(base + o);  o += 50056;
    int*      partials  = (int*)(base + o);  o += 256;
    unsigned* pk        = (unsigned*)(base + o); o += 800000;
    __half*   h1        = (__half*)(base + o);   o += 1600000;   // 50000*64 fp16
    __half*   h2        = (__half*)(base + o);   o += 1600000;
    float*    agg2      = base + o;          o += 3200000;
    int*      rank      = (int*)agg2;        // alias: rank dead before agg2 written
    float*    att_s     = base + o;          o += 50048;
    float*    gbuf      = base + o;          o += N_GRAPHS * HIDDEN;
    float*    t1        = base + o;          o += N_GRAPHS * EMBED;
    float*    t2        = base + o;          o += N_GRAPHS * 128;
    int*      gs        = (int*)(base + o);  o += 512;
    int*      ge        = (int*)(base + o);  o += 512;

    const int NB_N    = (N_NODES + 255) / 256;               // 196
    const int NB_E    = (N_EDGES + 255) / 256;               // 3125
    const int NB_ROW4 = N_NODES / 4;                         // 12500 (exact)
    const int NB_G32  = (N_NODES + G1_ROWS - 1) / G1_ROWS;   // 1563

    // CSR build
    k_zero<<<NB_N, 256, 0, stream>>>(deg_i, gs, ge);
    k_deg_rank<<<NB_E, 256, 0, stream>>>(e_dst, deg_i, rank);
    k_scan1<<<SCAN_BLOCKS, 256, 0, stream>>>(deg_i, row_start, partials, dis);
    k_scan2<<<1, 256, 0, stream>>>(partials);
    k_scan3<<<SCAN_BLOCKS, 256, 0, stream>>>(row_start, partials);
    k_fill<<<NB_E, 256, 0, stream>>>(e_src, e_dst, rank, row_start, dis, pk);

    // conv1 + conv2-transform
    k_gemm1<<<NB_G32, 256, 0, stream>>>(x, W1, h1);
    k_gg<<<NB_ROW4, 256, 0, stream>>>(h1, pk, row_start, dis, b1, W2, h2);

    // conv2-aggregate + attention score
    k_gather2<<<NB_ROW4, 256, 0, stream>>>(h2, pk, row_start, dis, b2, att_w, att_b,
                                           agg2, att_s);

    // pooling
    k_gbounds<<<NB_N, 256, 0, stream>>>(batch, gs, ge);
    k_pool<<<N_GRAPHS, 256, 0, stream>>>(agg2, att_s, gs, ge, gbuf);

    // head
    k_mlp1<<<(N_GRAPHS * EMBED + 255) / 256, 256, 0, stream>>>(gbuf, proj_w, proj_b, t1);
    k_mlp2<<<(N_GRAPHS * 128 + 255) / 256, 256, 0, stream>>>(t1, cls_w1, cls_b1, t2);
    k_mlp3<<<(N_GRAPHS * N_CLASSES + 255) / 256, 256, 0, stream>>>(t2, cls_w2, cls_b2, out);
}

// Round 6
// 205.124 us; speedup vs baseline: 2.7670x; 1.0528x over previous
//
#include <hip/hip_runtime.h>
#include <hip/hip_fp16.h>
#include <math.h>

#define N_NODES   50000
#define N_EDGES   800000
#define N_FEAT    128
#define HIDDEN    64
#define EMBED     300
#define N_CLASSES 10
#define N_GRAPHS  500
#define LEAKY     0.01f
#define SCAN_BLOCKS ((N_NODES + 255) / 256)  // 196
#define G1_ROWS   32

typedef __attribute__((ext_vector_type(4))) _Float16 half4f;

// packed edge: low 16 bits = src node id (50000 < 65536), high 16 = fp16 norm
__device__ __forceinline__ float pk_w(unsigned p) {
    return __half2float(__ushort_as_half((unsigned short)(p >> 16)));
}

// ---------------- init ----------------
__global__ void k_zero(int* deg, int* gs, int* ge) {
    int i = blockIdx.x * 256 + threadIdx.x;
    if (i < N_NODES) deg[i] = 0;
    if (i < N_GRAPHS) { gs[i] = 0; ge[i] = 0; }
}

// ---------------- degree count + per-edge rank (coalesced rank write) ----------------
__global__ void k_deg_rank(const int* __restrict__ dst, int* deg, int* rank) {
    int e = blockIdx.x * 256 + threadIdx.x;
    if (e < N_EDGES) rank[e] = atomicAdd(&deg[dst[e]], 1);
}

// ---------------- scan: deg -> row_start (exclusive); dis = rsqrt(deg+1) ----------------
__global__ __launch_bounds__(256) void k_scan1(const int* __restrict__ deg, int* row_start,
                                               int* partials, float* dis) {
    __shared__ int wsum[4];
    int i = blockIdx.x * 256 + threadIdx.x;
    int v = (i < N_NODES) ? deg[i] : 0;
    int lane = threadIdx.x & 63, wid = threadIdx.x >> 6;
    int s = v;
    #pragma unroll
    for (int off = 1; off < 64; off <<= 1) {
        int t = __shfl_up(s, off, 64);
        if (lane >= off) s += t;
    }
    if (lane == 63) wsum[wid] = s;
    __syncthreads();
    int woff = 0;
    for (int w = 0; w < wid; ++w) woff += wsum[w];
    if (i < N_NODES) {
        row_start[i] = woff + s - v;
        dis[i] = rsqrtf((float)(deg[i] + 1));
    }
    if (threadIdx.x == 255) partials[blockIdx.x] = woff + s;
}

__global__ __launch_bounds__(256) void k_scan2(int* partials) {
    __shared__ int wsum[4];
    int v = (threadIdx.x < SCAN_BLOCKS) ? partials[threadIdx.x] : 0;
    int lane = threadIdx.x & 63, wid = threadIdx.x >> 6;
    int s = v;
    #pragma unroll
    for (int off = 1; off < 64; off <<= 1) {
        int t = __shfl_up(s, off, 64);
        if (lane >= off) s += t;
    }
    if (lane == 63) wsum[wid] = s;
    __syncthreads();
    int woff = 0;
    for (int w = 0; w < wid; ++w) woff += wsum[w];
    if (threadIdx.x < SCAN_BLOCKS) partials[threadIdx.x] = woff + s - v;
}

__global__ void k_scan3(int* row_start, const int* __restrict__ partials) {
    int i = blockIdx.x * 256 + threadIdx.x;
    if (i < N_NODES) row_start[i] += partials[blockIdx.x];
    if (i == 0) row_start[N_NODES] = N_EDGES;
}

// ---------------- CSR fill: one packed 4B scatter per edge ----------------
__global__ void k_fill(const int* __restrict__ src, const int* __restrict__ dst,
                       const int* __restrict__ rank, const int* __restrict__ row_start,
                       const float* __restrict__ dis, unsigned* __restrict__ pk) {
    int e = blockIdx.x * 256 + threadIdx.x;
    if (e < N_EDGES) {
        int s = src[e], d = dst[e];
        float w = dis[s] * dis[d];
        unsigned short wh = __half_as_ushort(__float2half(w));
        pk[row_start[d] + rank[e]] = (unsigned)s | ((unsigned)wh << 16);
    }
}

// ---------------- GEMM1: h1 = x @ W1 (fp16 out), 32 rows/block ----------------
__global__ __launch_bounds__(256) void k_gemm1(const float* __restrict__ x,
                                               const float* __restrict__ W,
                                               __half* __restrict__ h) {
    __shared__ float sW[N_FEAT * HIDDEN];   // 32 KB
    __shared__ float sx[G1_ROWS * N_FEAT];  // 16 KB
    {
        const float4* W4 = (const float4*)W;
        float4* sW4 = (float4*)sW;
        #pragma unroll
        for (int i = 0; i < N_FEAT * HIDDEN / 4 / 256; ++i)
            sW4[i * 256 + threadIdx.x] = W4[i * 256 + threadIdx.x];

        int base = blockIdx.x * G1_ROWS;
        const float4* x4 = (const float4*)(x + (size_t)base * N_FEAT);
        float4* sx4 = (float4*)sx;
        int lim = (N_NODES - base) * (N_FEAT / 4);
        #pragma unroll
        for (int i = 0; i < G1_ROWS * N_FEAT / 4 / 256; ++i) {
            int idx = i * 256 + threadIdx.x;
            sx4[idx] = (idx < lim) ? x4[idx] : make_float4(0.f, 0.f, 0.f, 0.f);
        }
    }
    __syncthreads();

    int f = threadIdx.x & 63, wid = threadIdx.x >> 6;
    float acc[8];
    #pragma unroll
    for (int u = 0; u < 8; ++u) acc[u] = 0.0f;

    const float4* sx4 = (const float4*)sx;
    #pragma unroll 4
    for (int k4 = 0; k4 < N_FEAT / 4; ++k4) {
        float w0 = sW[(k4 * 4 + 0) * HIDDEN + f];
        float w1 = sW[(k4 * 4 + 1) * HIDDEN + f];
        float w2 = sW[(k4 * 4 + 2) * HIDDEN + f];
        float w3 = sW[(k4 * 4 + 3) * HIDDEN + f];
        #pragma unroll
        for (int u = 0; u < 8; ++u) {
            float4 xv = sx4[(wid * 8 + u) * (N_FEAT / 4) + k4];
            acc[u] = fmaf(xv.x, w0, fmaf(xv.y, w1, fmaf(xv.z, w2, fmaf(xv.w, w3, acc[u]))));
        }
    }
    int base = blockIdx.x * G1_ROWS;
    #pragma unroll
    for (int u = 0; u < 8; ++u) {
        int n = base + wid * 8 + u;
        if (n < N_NODES) h[(size_t)n * HIDDEN + f] = __float2half(acc[u]);
    }
}

// ---------------- gather core: 4 edges per wave-instruction ----------------
// lane = [g4 = edge slot (lane>>4)][q = feature quad (lane&15)], 8B loads
__device__ __forceinline__ void gather4(const __half* __restrict__ h,
                                        const unsigned* __restrict__ pk,
                                        int s, int e, int g4, int q, float4& acc) {
    for (int j = s; j < e; j += 4) {
        int idx = j + g4;
        unsigned p = (idx < e) ? pk[idx] : 0u;
        float w = pk_w(p);
        half4f hv = *(const half4f*)(h + ((size_t)(p & 0xFFFFu)) * HIDDEN + (q << 2));
        acc.x = fmaf(w, (float)hv.x, acc.x);
        acc.y = fmaf(w, (float)hv.y, acc.y);
        acc.z = fmaf(w, (float)hv.z, acc.z);
        acc.w = fmaf(w, (float)hv.w, acc.w);
    }
}

__device__ __forceinline__ void xreduce(float4& a) {
    a.x += __shfl_xor(a.x, 16, 64); a.y += __shfl_xor(a.y, 16, 64);
    a.z += __shfl_xor(a.z, 16, 64); a.w += __shfl_xor(a.w, 16, 64);
    a.x += __shfl_xor(a.x, 32, 64); a.y += __shfl_xor(a.y, 32, 64);
    a.z += __shfl_xor(a.z, 32, 64); a.w += __shfl_xor(a.w, 32, 64);
}

// ---------------- fused conv1-gather + gemm2, 16 nodes/block ----------------
__global__ __launch_bounds__(256) void k_gg(const __half* __restrict__ h1,
                                            const unsigned* __restrict__ pk,
                                            const int* __restrict__ row_start,
                                            const float* __restrict__ dis,
                                            const float* __restrict__ b1,
                                            const float* __restrict__ W2,
                                            __half* __restrict__ h2) {
    __shared__ float sW[HIDDEN * HIDDEN];  // 16 KB
    __shared__ float sa[16 * HIDDEN];      // 4 KB
    {
        const float4* W4 = (const float4*)W2;
        float4* sW4 = (float4*)sW;
        #pragma unroll
        for (int i = 0; i < 4; ++i)
            sW4[i * 256 + threadIdx.x] = W4[i * 256 + threadIdx.x];
    }

    int tid = threadIdx.x, wid = tid >> 6, lane = tid & 63;
    int g4 = lane >> 4, q = lane & 15;
    int base = blockIdx.x * 16 + wid * 4;   // grid exact: 50000 = 3125*16
    #pragma unroll
    for (int i = 0; i < 4; ++i) {
        int node = base + i;
        int s = row_start[node], e = row_start[node + 1];
        float4 acc = {0.f, 0.f, 0.f, 0.f};
        gather4(h1, pk, s, e, g4, q, acc);
        xreduce(acc);
        float dv = dis[node], dd = dv * dv;
        half4f sv = *(const half4f*)(h1 + (size_t)node * HIDDEN + (q << 2));
        float4 bv = *(const float4*)(b1 + (q << 2));
        float4 r;
        r.x = fmaxf(fmaf((float)sv.x, dd, bv.x) + acc.x, 0.f);
        r.y = fmaxf(fmaf((float)sv.y, dd, bv.y) + acc.y, 0.f);
        r.z = fmaxf(fmaf((float)sv.z, dd, bv.z) + acc.z, 0.f);
        r.w = fmaxf(fmaf((float)sv.w, dd, bv.w) + acc.w, 0.f);
        if (g4 == 0) *(float4*)&sa[(wid * 4 + i) * HIDDEN + (q << 2)] = r;
    }
    __syncthreads();

    // joint 4-node matvec: one sW read feeds 4 FMAs
    int f = lane;
    float o0 = 0.f, o1 = 0.f, o2 = 0.f, o3 = 0.f;
    const float* sa0 = &sa[wid * 4 * HIDDEN];
    #pragma unroll 8
    for (int k = 0; k < HIDDEN; ++k) {
        float wv = sW[k * HIDDEN + f];
        o0 = fmaf(sa0[k], wv, o0);
        o1 = fmaf(sa0[HIDDEN + k], wv, o1);
        o2 = fmaf(sa0[2 * HIDDEN + k], wv, o2);
        o3 = fmaf(sa0[3 * HIDDEN + k], wv, o3);
    }
    h2[(size_t)(base + 0) * HIDDEN + f] = __float2half(o0);
    h2[(size_t)(base + 1) * HIDDEN + f] = __float2half(o1);
    h2[(size_t)(base + 2) * HIDDEN + f] = __float2half(o2);
    h2[(size_t)(base + 3) * HIDDEN + f] = __float2half(o3);
}

// ---------------- conv2-gather + fused attention score, 1 node/wave ----------------
__global__ __launch_bounds__(256) void k_gather2(const __half* __restrict__ h2,
                                                 const unsigned* __restrict__ pk,
                                                 const int* __restrict__ row_start,
                                                 const float* __restrict__ dis,
                                                 const float* __restrict__ b2,
                                                 const float* __restrict__ att_w,
                                                 const float* __restrict__ att_b,
                                                 float* __restrict__ agg2,
                                                 float* __restrict__ att_s) {
    int tid = threadIdx.x, wid = tid >> 6, lane = tid & 63;
    int g4 = lane >> 4, q = lane & 15;
    int node = blockIdx.x * 4 + wid;   // grid exact: 12500*4 = 50000
    int s = row_start[node], e = row_start[node + 1];
    float4 acc = {0.f, 0.f, 0.f, 0.f};
    gather4(h2, pk, s, e, g4, q, acc);
    xreduce(acc);
    float dv = dis[node], dd = dv * dv;
    half4f sv = *(const half4f*)(h2 + (size_t)node * HIDDEN + (q << 2));
    float4 bv = *(const float4*)(b2 + (q << 2));
    float4 r;
    r.x = fmaxf(fmaf((float)sv.x, dd, bv.x) + acc.x, 0.f);
    r.y = fmaxf(fmaf((float)sv.y, dd, bv.y) + acc.y, 0.f);
    r.z = fmaxf(fmaf((float)sv.z, dd, bv.z) + acc.z, 0.f);
    r.w = fmaxf(fmaf((float)sv.w, dd, bv.w) + acc.w, 0.f);
    if (g4 == 0) *(float4*)(agg2 + (size_t)node * HIDDEN + (q << 2)) = r;

    float4 aw = *(const float4*)(att_w + (q << 2));
    float v = fmaf(r.x, aw.x, fmaf(r.y, aw.y, fmaf(r.z, aw.z, r.w * aw.w)));
    v += __shfl_xor(v, 1, 64); v += __shfl_xor(v, 2, 64);
    v += __shfl_xor(v, 4, 64); v += __shfl_xor(v, 8, 64);
    if (lane == 0) {
        float sc = v + att_b[0];
        att_s[node] = (sc > 0.0f) ? sc : LEAKY * sc;
    }
}

// ---------------- graph boundaries (batch sorted) ----------------
__global__ void k_gbounds(const int* __restrict__ batch, int* gs, int* ge) {
    int n = blockIdx.x * 256 + threadIdx.x;
    if (n < N_NODES) {
        int b = batch[n];
        if (n == 0 || batch[n - 1] != b) gs[b] = n;
        if (n == N_NODES - 1 || batch[n + 1] != b) ge[b] = n + 1;
    }
}

// ---------------- fused pool + head MLPs: one block per graph ----------------
__global__ __launch_bounds__(256) void k_pool_head(const float* __restrict__ agg2,
                                                   const float* __restrict__ att_s,
                                                   const int* __restrict__ gs,
                                                   const int* __restrict__ ge,
                                                   const float* __restrict__ proj_w,
                                                   const float* __restrict__ proj_b,
                                                   const float* __restrict__ cls_w1,
                                                   const float* __restrict__ cls_b1,
                                                   const float* __restrict__ cls_w2,
                                                   const float* __restrict__ cls_b2,
                                                   float* __restrict__ out) {
    __shared__ float red[4];
    __shared__ float red2[4 * 64];
    __shared__ float sG[HIDDEN];
    __shared__ float sT1[EMBED];
    __shared__ float sT2[128];
    int gid = blockIdx.x;
    int tid = threadIdx.x, f = tid & 63, w = tid >> 6;
    int s = gs[gid], e = ge[gid];

    // segment max
    float m = -INFINITY;
    for (int n = s + tid; n < e; n += 256) m = fmaxf(m, att_s[n]);
    #pragma unroll
    for (int o = 32; o > 0; o >>= 1) m = fmaxf(m, __shfl_xor(m, o, 64));
    if (f == 0) red[w] = m;
    __syncthreads();
    m = fmaxf(fmaxf(red[0], red[1]), fmaxf(red[2], red[3]));
    __syncthreads();

    // denom
    float z = 0.0f;
    for (int n = s + tid; n < e; n += 256) z += expf(att_s[n] - m);
    #pragma unroll
    for (int o = 32; o > 0; o >>= 1) z += __shfl_xor(z, o, 64);
    if (f == 0) red[w] = z;
    __syncthreads();
    z = red[0] + red[1] + red[2] + red[3];
    float inv = (e > s) ? 1.0f / z : 0.0f;

    // weighted sum
    float acc = 0.0f;
    for (int n = s + w; n < e; n += 4)
        acc = fmaf(expf(att_s[n] - m) * inv, agg2[(size_t)n * HIDDEN + f], acc);
    red2[w * 64 + f] = acc;
    __syncthreads();
    if (w == 0) sG[f] = red2[f] + red2[64 + f] + red2[128 + f] + red2[192 + f];
    __syncthreads();

    // t1 = g @ proj_w + proj_b   (rows of proj_w are contiguous -> coalesced)
    for (int c = tid; c < EMBED; c += 256) {
        float a = proj_b[c];
        #pragma unroll 8
        for (int k = 0; k < HIDDEN; ++k) a = fmaf(sG[k], proj_w[k * EMBED + c], a);
        sT1[c] = a;
    }
    __syncthreads();

    // t2 = relu(t1 @ cls_w1 + cls_b1)
    if (tid < 128) {
        float a = cls_b1[tid];
        for (int k = 0; k < EMBED; ++k) a = fmaf(sT1[k], cls_w1[k * 128 + tid], a);
        sT2[tid] = fmaxf(a, 0.f);
    }
    __syncthreads();

    // out = t2 @ cls_w2 + cls_b2
    if (tid < N_CLASSES) {
        float a = cls_b2[tid];
        #pragma unroll 8
        for (int k = 0; k < 128; ++k) a = fmaf(sT2[k], cls_w2[k * N_CLASSES + tid], a);
        out[gid * N_CLASSES + tid] = a;
    }
}

extern "C" void kernel_launch(void* const* d_in, const int* in_sizes, int n_in,
                              void* d_out, int out_size, void* d_ws, size_t ws_size,
                              hipStream_t stream) {
    const float* x      = (const float*)d_in[0];
    const int*   ei     = (const int*)d_in[1];
    const int*   batch  = (const int*)d_in[2];
    const float* W1     = (const float*)d_in[3];
    const float* b1     = (const float*)d_in[4];
    const float* W2     = (const float*)d_in[5];
    const float* b2     = (const float*)d_in[6];
    const float* att_w  = (const float*)d_in[7];
    const float* att_b  = (const float*)d_in[8];
    const float* proj_w = (const float*)d_in[9];
    const float* proj_b = (const float*)d_in[10];
    const float* cls_w1 = (const float*)d_in[11];
    const float* cls_b1 = (const float*)d_in[12];
    const float* cls_w2 = (const float*)d_in[13];
    const float* cls_b2 = (const float*)d_in[14];
    float* out = (float*)d_out;

    const int* e_src = ei;
    const int* e_dst = ei + N_EDGES;

    // workspace layout (float words; h1/h2 are fp16 so 50000*64 halves = 1.6M words each)
    float* base = (float*)d_ws;
    size_t o = 0;
    float*    dis       = base + o;              o += 50048;
    int*      deg_i     = (int*)(base + o);      o += 50048;
    int*      row_start = (int*)(base + o);      o += 50056;
    int*      partials  = (int*)(base + o);      o += 256;
    unsigned* pk        = (unsigned*)(base + o); o += 800000;
    __half*   h1        = (__half*)(base + o);   o += 1600000;   // 50000*64 fp16 = 6.4 MB
    __half*   h2        = (__half*)(base + o);   o += 1600000;
    float*    agg2      = base + o;              o += 3200000;
    int*      rank      = (int*)agg2;            // alias: rank dead before agg2 written
    float*    att_s     = base + o;              o += 50048;
    int*      gs        = (int*)(base + o);      o += 512;
    int*      ge        = (int*)(base + o);      o += 512;

    const int NB_N    = (N_NODES + 255) / 256;               // 196
    const int NB_E    = (N_EDGES + 255) / 256;               // 3125
    const int NB_GG   = N_NODES / 16;                        // 3125 (exact)
    const int NB_ROW4 = N_NODES / 4;                         // 12500 (exact)
    const int NB_G32  = (N_NODES + G1_ROWS - 1) / G1_ROWS;   // 1563

    // CSR build
    k_zero<<<NB_N, 256, 0, stream>>>(deg_i, gs, ge);
    k_deg_rank<<<NB_E, 256, 0, stream>>>(e_dst, deg_i, rank);
    k_scan1<<<SCAN_BLOCKS, 256, 0, stream>>>(deg_i, row_start, partials, dis);
    k_scan2<<<1, 256, 0, stream>>>(partials);
    k_scan3<<<SCAN_BLOCKS, 256, 0, stream>>>(row_start, partials);
    k_fill<<<NB_E, 256, 0, stream>>>(e_src, e_dst, rank, row_start, dis, pk);

    // conv1 + conv2-transform
    k_gemm1<<<NB_G32, 256, 0, stream>>>(x, W1, h1);
    k_gg<<<NB_GG, 256, 0, stream>>>(h1, pk, row_start, dis, b1, W2, h2);

    // conv2-aggregate + attention score
    k_gather2<<<NB_ROW4, 256, 0, stream>>>(h2, pk, row_start, dis, b2, att_w, att_b,
                                           agg2, att_s);

    // pooling + head (fused)
    k_gbounds<<<NB_N, 256, 0, stream>>>(batch, gs, ge);
    k_pool_head<<<N_GRAPHS, 256, 0, stream>>>(agg2, att_s, gs, ge,
                                              proj_w, proj_b, cls_w1, cls_b1,
                                              cls_w2, cls_b2, out);
}

// Round 7
// 193.503 us; speedup vs baseline: 2.9332x; 1.0601x over previous
//
#include <hip/hip_runtime.h>
#include <hip/hip_fp16.h>
#include <math.h>

#define N_NODES   50000
#define N_EDGES   800000
#define N_FEAT    128
#define HIDDEN    64
#define EMBED     300
#define N_CLASSES 10
#define N_GRAPHS  500
#define LEAKY     0.01f
#define SCAN_BLOCKS ((N_NODES + 255) / 256)  // 196
#define G1_ROWS   32

typedef __attribute__((ext_vector_type(4))) _Float16 half4f;

// packed edge: low 16 bits = src node id (50000 < 65536), high 16 = fp16 norm
__device__ __forceinline__ float pk_w(unsigned p) {
    return __half2float(__ushort_as_half((unsigned short)(p >> 16)));
}

// ---------------- init ----------------
__global__ void k_zero(int* deg, int* gs, int* ge) {
    int i = blockIdx.x * 256 + threadIdx.x;
    if (i < N_NODES) deg[i] = 0;
    if (i < N_GRAPHS) { gs[i] = 0; ge[i] = 0; }
}

// ---------------- degree count + per-edge rank (coalesced rank write) ----------------
__global__ void k_deg_rank(const int* __restrict__ dst, int* deg, int* rank) {
    int e = blockIdx.x * 256 + threadIdx.x;
    if (e < N_EDGES) rank[e] = atomicAdd(&deg[dst[e]], 1);
}

// ---------------- scan: deg -> row_start (exclusive); dis = rsqrt(deg+1) ----------------
__global__ __launch_bounds__(256) void k_scan1(const int* __restrict__ deg, int* row_start,
                                               int* partials, float* dis) {
    __shared__ int wsum[4];
    int i = blockIdx.x * 256 + threadIdx.x;
    int v = (i < N_NODES) ? deg[i] : 0;
    int lane = threadIdx.x & 63, wid = threadIdx.x >> 6;
    int s = v;
    #pragma unroll
    for (int off = 1; off < 64; off <<= 1) {
        int t = __shfl_up(s, off, 64);
        if (lane >= off) s += t;
    }
    if (lane == 63) wsum[wid] = s;
    __syncthreads();
    int woff = 0;
    for (int w = 0; w < wid; ++w) woff += wsum[w];
    if (i < N_NODES) {
        row_start[i] = woff + s - v;
        dis[i] = rsqrtf((float)(deg[i] + 1));
    }
    if (threadIdx.x == 255) partials[blockIdx.x] = woff + s;
}

__global__ __launch_bounds__(256) void k_scan2(int* partials) {
    __shared__ int wsum[4];
    int v = (threadIdx.x < SCAN_BLOCKS) ? partials[threadIdx.x] : 0;
    int lane = threadIdx.x & 63, wid = threadIdx.x >> 6;
    int s = v;
    #pragma unroll
    for (int off = 1; off < 64; off <<= 1) {
        int t = __shfl_up(s, off, 64);
        if (lane >= off) s += t;
    }
    if (lane == 63) wsum[wid] = s;
    __syncthreads();
    int woff = 0;
    for (int w = 0; w < wid; ++w) woff += wsum[w];
    if (threadIdx.x < SCAN_BLOCKS) partials[threadIdx.x] = woff + s - v;
}

__global__ void k_scan3(int* row_start, const int* __restrict__ partials) {
    int i = blockIdx.x * 256 + threadIdx.x;
    if (i < N_NODES) row_start[i] += partials[blockIdx.x];
    if (i == 0) row_start[N_NODES] = N_EDGES;
}

// ---------------- CSR fill: one packed 4B scatter per edge ----------------
__global__ void k_fill(const int* __restrict__ src, const int* __restrict__ dst,
                       const int* __restrict__ rank, const int* __restrict__ row_start,
                       const float* __restrict__ dis, unsigned* __restrict__ pk) {
    int e = blockIdx.x * 256 + threadIdx.x;
    if (e < N_EDGES) {
        int s = src[e], d = dst[e];
        float w = dis[s] * dis[d];
        unsigned short wh = __half_as_ushort(__float2half(w));
        pk[row_start[d] + rank[e]] = (unsigned)s | ((unsigned)wh << 16);
    }
}

// ---------------- GEMM1: h1 = x @ W1 (fp16 out), 32 rows/block ----------------
__global__ __launch_bounds__(256) void k_gemm1(const float* __restrict__ x,
                                               const float* __restrict__ W,
                                               __half* __restrict__ h) {
    __shared__ float sW[N_FEAT * HIDDEN];   // 32 KB
    __shared__ float sx[G1_ROWS * N_FEAT];  // 16 KB
    {
        const float4* W4 = (const float4*)W;
        float4* sW4 = (float4*)sW;
        #pragma unroll
        for (int i = 0; i < N_FEAT * HIDDEN / 4 / 256; ++i)
            sW4[i * 256 + threadIdx.x] = W4[i * 256 + threadIdx.x];

        int base = blockIdx.x * G1_ROWS;
        const float4* x4 = (const float4*)(x + (size_t)base * N_FEAT);
        float4* sx4 = (float4*)sx;
        int lim = (N_NODES - base) * (N_FEAT / 4);
        #pragma unroll
        for (int i = 0; i < G1_ROWS * N_FEAT / 4 / 256; ++i) {
            int idx = i * 256 + threadIdx.x;
            sx4[idx] = (idx < lim) ? x4[idx] : make_float4(0.f, 0.f, 0.f, 0.f);
        }
    }
    __syncthreads();

    int f = threadIdx.x & 63, wid = threadIdx.x >> 6;
    float acc[8];
    #pragma unroll
    for (int u = 0; u < 8; ++u) acc[u] = 0.0f;

    const float4* sx4 = (const float4*)sx;
    #pragma unroll 4
    for (int k4 = 0; k4 < N_FEAT / 4; ++k4) {
        float w0 = sW[(k4 * 4 + 0) * HIDDEN + f];
        float w1 = sW[(k4 * 4 + 1) * HIDDEN + f];
        float w2 = sW[(k4 * 4 + 2) * HIDDEN + f];
        float w3 = sW[(k4 * 4 + 3) * HIDDEN + f];
        #pragma unroll
        for (int u = 0; u < 8; ++u) {
            float4 xv = sx4[(wid * 8 + u) * (N_FEAT / 4) + k4];
            acc[u] = fmaf(xv.x, w0, fmaf(xv.y, w1, fmaf(xv.z, w2, fmaf(xv.w, w3, acc[u]))));
        }
    }
    int base = blockIdx.x * G1_ROWS;
    #pragma unroll
    for (int u = 0; u < 8; ++u) {
        int n = base + wid * 8 + u;
        if (n < N_NODES) h[(size_t)n * HIDDEN + f] = __float2half(acc[u]);
    }
}

// ---------------- gather core: coalesced pk preload + shfl broadcast ----------------
// lane = [g4 = edge slot (lane>>4)][q = feature quad (lane&15)], 8B h loads.
// One coalesced pk load per 64-edge chunk; h addresses then register-only ->
// many independent h loads in flight.
__device__ __forceinline__ void gather4pk(const __half* __restrict__ h,
                                          const unsigned* __restrict__ pk,
                                          int s, int e, int lane, int g4, int q,
                                          float4& acc) {
    for (int cs = s; cs < e; cs += 64) {
        unsigned pkv = (cs + lane < e) ? pk[cs + lane] : 0u;
        int avail = e - cs; if (avail > 64) avail = 64;
        int iters = (avail + 3) >> 2;
        #pragma unroll 2
        for (int t = 0; t < iters; ++t) {
            unsigned p = __shfl(pkv, t * 4 + g4, 64);   // w=0 for padded slots
            float w = pk_w(p);
            half4f hv = *(const half4f*)(h + ((size_t)(p & 0xFFFFu)) * HIDDEN + (q << 2));
            acc.x = fmaf(w, (float)hv.x, acc.x);
            acc.y = fmaf(w, (float)hv.y, acc.y);
            acc.z = fmaf(w, (float)hv.z, acc.z);
            acc.w = fmaf(w, (float)hv.w, acc.w);
        }
    }
}

__device__ __forceinline__ void xreduce(float4& a) {
    a.x += __shfl_xor(a.x, 16, 64); a.y += __shfl_xor(a.y, 16, 64);
    a.z += __shfl_xor(a.z, 16, 64); a.w += __shfl_xor(a.w, 16, 64);
    a.x += __shfl_xor(a.x, 32, 64); a.y += __shfl_xor(a.y, 32, 64);
    a.z += __shfl_xor(a.z, 32, 64); a.w += __shfl_xor(a.w, 32, 64);
}

// ---------------- fused conv1-gather + gemm2, 16 nodes/block ----------------
__global__ __launch_bounds__(256) void k_gg(const __half* __restrict__ h1,
                                            const unsigned* __restrict__ pk,
                                            const int* __restrict__ row_start,
                                            const float* __restrict__ dis,
                                            const float* __restrict__ b1,
                                            const float* __restrict__ W2,
                                            __half* __restrict__ h2) {
    __shared__ float sW[HIDDEN * HIDDEN];  // 16 KB
    __shared__ float sa[16 * HIDDEN];      // 4 KB
    {
        const float4* W4 = (const float4*)W2;
        float4* sW4 = (float4*)sW;
        #pragma unroll
        for (int i = 0; i < 4; ++i)
            sW4[i * 256 + threadIdx.x] = W4[i * 256 + threadIdx.x];
    }

    int tid = threadIdx.x, wid = tid >> 6, lane = tid & 63;
    int g4 = lane >> 4, q = lane & 15;
    int base = blockIdx.x * 16 + wid * 4;   // grid exact: 50000 = 3125*16
    #pragma unroll
    for (int i = 0; i < 4; ++i) {
        int node = base + i;
        int s = row_start[node], e = row_start[node + 1];
        float4 acc = {0.f, 0.f, 0.f, 0.f};
        gather4pk(h1, pk, s, e, lane, g4, q, acc);
        xreduce(acc);
        float dv = dis[node], dd = dv * dv;
        half4f sv = *(const half4f*)(h1 + (size_t)node * HIDDEN + (q << 2));
        float4 bv = *(const float4*)(b1 + (q << 2));
        float4 r;
        r.x = fmaxf(fmaf((float)sv.x, dd, bv.x) + acc.x, 0.f);
        r.y = fmaxf(fmaf((float)sv.y, dd, bv.y) + acc.y, 0.f);
        r.z = fmaxf(fmaf((float)sv.z, dd, bv.z) + acc.z, 0.f);
        r.w = fmaxf(fmaf((float)sv.w, dd, bv.w) + acc.w, 0.f);
        if (g4 == 0) *(float4*)&sa[(wid * 4 + i) * HIDDEN + (q << 2)] = r;
    }
    __syncthreads();

    // joint 4-node matvec: one sW read feeds 4 FMAs
    int f = lane;
    float o0 = 0.f, o1 = 0.f, o2 = 0.f, o3 = 0.f;
    const float* sa0 = &sa[wid * 4 * HIDDEN];
    #pragma unroll 8
    for (int k = 0; k < HIDDEN; ++k) {
        float wv = sW[k * HIDDEN + f];
        o0 = fmaf(sa0[k], wv, o0);
        o1 = fmaf(sa0[HIDDEN + k], wv, o1);
        o2 = fmaf(sa0[2 * HIDDEN + k], wv, o2);
        o3 = fmaf(sa0[3 * HIDDEN + k], wv, o3);
    }
    h2[(size_t)(base + 0) * HIDDEN + f] = __float2half(o0);
    h2[(size_t)(base + 1) * HIDDEN + f] = __float2half(o1);
    h2[(size_t)(base + 2) * HIDDEN + f] = __float2half(o2);
    h2[(size_t)(base + 3) * HIDDEN + f] = __float2half(o3);
}

// ---------------- conv2-gather + fused attention score, 1 node/wave ----------------
__global__ __launch_bounds__(256) void k_gather2(const __half* __restrict__ h2,
                                                 const unsigned* __restrict__ pk,
                                                 const int* __restrict__ row_start,
                                                 const float* __restrict__ dis,
                                                 const float* __restrict__ b2,
                                                 const float* __restrict__ att_w,
                                                 const float* __restrict__ att_b,
                                                 float* __restrict__ agg2,
                                                 float* __restrict__ att_s) {
    int tid = threadIdx.x, wid = tid >> 6, lane = tid & 63;
    int g4 = lane >> 4, q = lane & 15;
    int node = blockIdx.x * 4 + wid;   // grid exact: 12500*4 = 50000
    int s = row_start[node], e = row_start[node + 1];
    float4 acc = {0.f, 0.f, 0.f, 0.f};
    gather4pk(h2, pk, s, e, lane, g4, q, acc);
    xreduce(acc);
    float dv = dis[node], dd = dv * dv;
    half4f sv = *(const half4f*)(h2 + (size_t)node * HIDDEN + (q << 2));
    float4 bv = *(const float4*)(b2 + (q << 2));
    float4 r;
    r.x = fmaxf(fmaf((float)sv.x, dd, bv.x) + acc.x, 0.f);
    r.y = fmaxf(fmaf((float)sv.y, dd, bv.y) + acc.y, 0.f);
    r.z = fmaxf(fmaf((float)sv.z, dd, bv.z) + acc.z, 0.f);
    r.w = fmaxf(fmaf((float)sv.w, dd, bv.w) + acc.w, 0.f);
    if (g4 == 0) *(float4*)(agg2 + (size_t)node * HIDDEN + (q << 2)) = r;

    float4 aw = *(const float4*)(att_w + (q << 2));
    float v = fmaf(r.x, aw.x, fmaf(r.y, aw.y, fmaf(r.z, aw.z, r.w * aw.w)));
    v += __shfl_xor(v, 1, 64); v += __shfl_xor(v, 2, 64);
    v += __shfl_xor(v, 4, 64); v += __shfl_xor(v, 8, 64);
    if (lane == 0) {
        float sc = v + att_b[0];
        att_s[node] = (sc > 0.0f) ? sc : LEAKY * sc;
    }
}

// ---------------- graph boundaries (batch sorted) ----------------
__global__ void k_gbounds(const int* __restrict__ batch, int* gs, int* ge) {
    int n = blockIdx.x * 256 + threadIdx.x;
    if (n < N_NODES) {
        int b = batch[n];
        if (n == 0 || batch[n - 1] != b) gs[b] = n;
        if (n == N_NODES - 1 || batch[n + 1] != b) ge[b] = n + 1;
    }
}

// ---------------- fused pool + head MLPs: one block per graph ----------------
__global__ __launch_bounds__(256) void k_pool_head(const float* __restrict__ agg2,
                                                   const float* __restrict__ att_s,
                                                   const int* __restrict__ gs,
                                                   const int* __restrict__ ge,
                                                   const float* __restrict__ proj_w,
                                                   const float* __restrict__ proj_b,
                                                   const float* __restrict__ cls_w1,
                                                   const float* __restrict__ cls_b1,
                                                   const float* __restrict__ cls_w2,
                                                   const float* __restrict__ cls_b2,
                                                   float* __restrict__ out) {
    __shared__ float red[4];
    __shared__ float red2[4 * 64];
    __shared__ float sG[HIDDEN];
    __shared__ float sT1[EMBED];
    __shared__ float sT2[128];
    int gid = blockIdx.x;
    int tid = threadIdx.x, f = tid & 63, w = tid >> 6;
    int s = gs[gid], e = ge[gid];

    // segment max
    float m = -INFINITY;
    for (int n = s + tid; n < e; n += 256) m = fmaxf(m, att_s[n]);
    #pragma unroll
    for (int o = 32; o > 0; o >>= 1) m = fmaxf(m, __shfl_xor(m, o, 64));
    if (f == 0) red[w] = m;
    __syncthreads();
    m = fmaxf(fmaxf(red[0], red[1]), fmaxf(red[2], red[3]));
    __syncthreads();

    // denom
    float z = 0.0f;
    for (int n = s + tid; n < e; n += 256) z += expf(att_s[n] - m);
    #pragma unroll
    for (int o = 32; o > 0; o >>= 1) z += __shfl_xor(z, o, 64);
    if (f == 0) red[w] = z;
    __syncthreads();
    z = red[0] + red[1] + red[2] + red[3];
    float inv = (e > s) ? 1.0f / z : 0.0f;

    // weighted sum
    float acc = 0.0f;
    for (int n = s + w; n < e; n += 4)
        acc = fmaf(expf(att_s[n] - m) * inv, agg2[(size_t)n * HIDDEN + f], acc);
    red2[w * 64 + f] = acc;
    __syncthreads();
    if (w == 0) sG[f] = red2[f] + red2[64 + f] + red2[128 + f] + red2[192 + f];
    __syncthreads();

    // t1 = g @ proj_w + proj_b
    for (int c = tid; c < EMBED; c += 256) {
        float a = proj_b[c];
        #pragma unroll 8
        for (int k = 0; k < HIDDEN; ++k) a = fmaf(sG[k], proj_w[k * EMBED + c], a);
        sT1[c] = a;
    }
    __syncthreads();

    // t2 = relu(t1 @ cls_w1 + cls_b1)
    if (tid < 128) {
        float a = cls_b1[tid];
        for (int k = 0; k < EMBED; ++k) a = fmaf(sT1[k], cls_w1[k * 128 + tid], a);
        sT2[tid] = fmaxf(a, 0.f);
    }
    __syncthreads();

    // out = t2 @ cls_w2 + cls_b2
    if (tid < N_CLASSES) {
        float a = cls_b2[tid];
        #pragma unroll 8
        for (int k = 0; k < 128; ++k) a = fmaf(sT2[k], cls_w2[k * N_CLASSES + tid], a);
        out[gid * N_CLASSES + tid] = a;
    }
}

extern "C" void kernel_launch(void* const* d_in, const int* in_sizes, int n_in,
                              void* d_out, int out_size, void* d_ws, size_t ws_size,
                              hipStream_t stream) {
    const float* x      = (const float*)d_in[0];
    const int*   ei     = (const int*)d_in[1];
    const int*   batch  = (const int*)d_in[2];
    const float* W1     = (const float*)d_in[3];
    const float* b1     = (const float*)d_in[4];
    const float* W2     = (const float*)d_in[5];
    const float* b2     = (const float*)d_in[6];
    const float* att_w  = (const float*)d_in[7];
    const float* att_b  = (const float*)d_in[8];
    const float* proj_w = (const float*)d_in[9];
    const float* proj_b = (const float*)d_in[10];
    const float* cls_w1 = (const float*)d_in[11];
    const float* cls_b1 = (const float*)d_in[12];
    const float* cls_w2 = (const float*)d_in[13];
    const float* cls_b2 = (const float*)d_in[14];
    float* out = (float*)d_out;

    const int* e_src = ei;
    const int* e_dst = ei + N_EDGES;

    // workspace layout (float words; h1/h2 are fp16 so 50000*64 halves = 1.6M words each)
    float* base = (float*)d_ws;
    size_t o = 0;
    float*    dis       = base + o;              o += 50048;
    int*      deg_i     = (int*)(base + o);      o += 50048;
    int*      row_start = (int*)(base + o);      o += 50056;
    int*      partials  = (int*)(base + o);      o += 256;
    unsigned* pk        = (unsigned*)(base + o); o += 800000;
    __half*   h1        = (__half*)(base + o);   o += 1600000;   // 50000*64 fp16 = 6.4 MB
    __half*   h2        = (__half*)(base + o);   o += 1600000;
    float*    agg2      = base + o;              o += 3200000;
    int*      rank      = (int*)agg2;            // alias: rank dead before agg2 written
    float*    att_s     = base + o;              o += 50048;
    int*      gs        = (int*)(base + o);      o += 512;
    int*      ge        = (int*)(base + o);      o += 512;

    const int NB_N    = (N_NODES + 255) / 256;               // 196
    const int NB_E    = (N_EDGES + 255) / 256;               // 3125
    const int NB_GG   = N_NODES / 16;                        // 3125 (exact)
    const int NB_ROW4 = N_NODES / 4;                         // 12500 (exact)
    const int NB_G32  = (N_NODES + G1_ROWS - 1) / G1_ROWS;   // 1563

    // CSR build
    k_zero<<<NB_N, 256, 0, stream>>>(deg_i, gs, ge);
    k_deg_rank<<<NB_E, 256, 0, stream>>>(e_dst, deg_i, rank);
    k_scan1<<<SCAN_BLOCKS, 256, 0, stream>>>(deg_i, row_start, partials, dis);
    k_scan2<<<1, 256, 0, stream>>>(partials);
    k_scan3<<<SCAN_BLOCKS, 256, 0, stream>>>(row_start, partials);
    k_fill<<<NB_E, 256, 0, stream>>>(e_src, e_dst, rank, row_start, dis, pk);

    // conv1 + conv2-transform
    k_gemm1<<<NB_G32, 256, 0, stream>>>(x, W1, h1);
    k_gg<<<NB_GG, 256, 0, stream>>>(h1, pk, row_start, dis, b1, W2, h2);

    // conv2-aggregate + attention score
    k_gather2<<<NB_ROW4, 256, 0, stream>>>(h2, pk, row_start, dis, b2, att_w, att_b,
                                           agg2, att_s);

    // pooling + head (fused)
    k_gbounds<<<NB_N, 256, 0, stream>>>(batch, gs, ge);
    k_pool_head<<<N_GRAPHS, 256, 0, stream>>>(agg2, att_s, gs, ge,
                                              proj_w, proj_b, cls_w1, cls_b1,
                                              cls_w2, cls_b2, out);
}